// Round 7
// baseline (238.863 us; speedup 1.0000x reference)
//
#include <hip/hip_runtime.h>
#include <hip/hip_bf16.h>
#include <stdint.h>

typedef unsigned short u16;
typedef unsigned int u32;

#define D_MODEL 1024
#define NHEADS 16
#define DK 64
#define BB 4
#define SS 2048
#define M_TOT (BB * SS)  // 8192
#define QK_SCALE 0.18033688011112042f  // 0.125 * log2(e)

typedef __attribute__((ext_vector_type(8))) short short8;
typedef __attribute__((ext_vector_type(8))) __bf16 bf16x8;
typedef __attribute__((ext_vector_type(4))) float f32x4;

static __device__ __forceinline__ f32x4 mfma16(short8 a, short8 b, f32x4 c) {
  return __builtin_amdgcn_mfma_f32_16x16x32_bf16(
      __builtin_bit_cast(bf16x8, a), __builtin_bit_cast(bf16x8, b), c, 0, 0, 0);
}

// round-to-nearest-even f32 -> bf16
static __device__ __forceinline__ u16 f2bf(float f) {
  u32 u = __builtin_bit_cast(u32, f);
  u += 0x7fffu + ((u >> 16) & 1u);
  return (u16)(u >> 16);
}

// packed f32x2 -> bf16x2 (RNE), single instruction; dst.lo = lo, dst.hi = hi
static __device__ __forceinline__ u32 cvtpk(float lo, float hi) {
  u32 r;
  asm("v_cvt_pk_bf16_f32 %0, %1, %2" : "=v"(r) : "v"(lo), "v"(hi));
  return r;
}
// swap a.lanes[32:63] <-> b.lanes[0:31]   (vdst.hi32 <-> vsrc.lo32)
static __device__ __forceinline__ void pl32swap(u32& a, u32& b) {
  asm("v_permlane32_swap_b32 %0, %1" : "+v"(a), "+v"(b));
}
// swap a.odd-16-rows <-> b.even-16-rows
static __device__ __forceinline__ void pl16swap(u32& a, u32& b) {
  asm("v_permlane16_swap_b32 %0, %1" : "+v"(a), "+v"(b));
}

// ---------------- f32 -> bf16 converts (fused launches) ----------------
__global__ void cvt3_kernel(const float* __restrict__ s0, const float* __restrict__ s1,
                            const float* __restrict__ s2, u16* __restrict__ d0,
                            u16* __restrict__ d1, u16* __restrict__ d2, int n4) {
  const float* s = blockIdx.y == 0 ? s0 : blockIdx.y == 1 ? s1 : s2;
  u16* d = blockIdx.y == 0 ? d0 : blockIdx.y == 1 ? d1 : d2;
  int stride = gridDim.x * blockDim.x;
  for (int i = blockIdx.x * blockDim.x + threadIdx.x; i < n4; i += stride) {
    float4 v = reinterpret_cast<const float4*>(s)[i];
    ushort4 o;
    o.x = f2bf(v.x); o.y = f2bf(v.y); o.z = f2bf(v.z); o.w = f2bf(v.w);
    reinterpret_cast<ushort4*>(d)[i] = o;
  }
}
__global__ void cvt4_kernel(const float* __restrict__ s0, const float* __restrict__ s1,
                            const float* __restrict__ s2, const float* __restrict__ s3,
                            u16* __restrict__ d0, u16* __restrict__ d1,
                            u16* __restrict__ d2, u16* __restrict__ d3, int n4) {
  const float* s = blockIdx.y == 0 ? s0 : blockIdx.y == 1 ? s1 : blockIdx.y == 2 ? s2 : s3;
  u16* d = blockIdx.y == 0 ? d0 : blockIdx.y == 1 ? d1 : blockIdx.y == 2 ? d2 : d3;
  int stride = gridDim.x * blockDim.x;
  for (int i = blockIdx.x * blockDim.x + threadIdx.x; i < n4; i += stride) {
    float4 v = reinterpret_cast<const float4*>(s)[i];
    ushort4 o;
    o.x = f2bf(v.x); o.y = f2bf(v.y); o.z = f2bf(v.z); o.w = f2bf(v.w);
    reinterpret_cast<ushort4*>(d)[i] = o;
  }
}

// ---------------- NT GEMM: C[m,n] = sum_k A[m,k] * Bt[n,k] ----------------
// MODE 0: out bf16 [b,h,s,dk], scaled by oscale
// MODE 1: out bf16 [b,h,dk,s] (V transposed)
// MODE 2: out f32 row-major
template <int MODE>
__global__ __launch_bounds__(256, 2) void gemm_bt(const u16* __restrict__ A,
                                                  const u16* __restrict__ Bt,
                                                  void* __restrict__ out,
                                                  float oscale) {
  __shared__ __align__(16) u16 As[128 * 32];
  __shared__ __align__(16) u16 Bs[128 * 32];
  const int tid = threadIdx.x;
  const int l = tid & 63, w = tid >> 6;
  const int m0 = blockIdx.x * 128, n0 = blockIdx.y * 128;
  const int wr = w >> 1, wc = w & 1;
  const int lq = l & 15, hi = l >> 4;

  f32x4 acc[4][4] = {};

  const int row_t = tid >> 2;        // + c*64
  const int col8 = (tid & 3) * 8;

  for (int k0 = 0; k0 < 1024; k0 += 32) {
#pragma unroll
    for (int c = 0; c < 2; ++c) {
      int row = c * 64 + row_t;
      const u16* ga = A + (size_t)(m0 + row) * 1024 + k0 + col8;
      const u16* gb = Bt + (size_t)(n0 + row) * 1024 + k0 + col8;
      __builtin_amdgcn_global_load_lds(
          (const __attribute__((address_space(1))) void*)ga,
          (__attribute__((address_space(3))) void*)&As[(c * 256 + w * 64) * 8], 16, 0, 0);
      __builtin_amdgcn_global_load_lds(
          (const __attribute__((address_space(1))) void*)gb,
          (__attribute__((address_space(3))) void*)&Bs[(c * 256 + w * 64) * 8], 16, 0, 0);
    }
    __syncthreads();
    short8 af[4], bf[4];
#pragma unroll
    for (int i = 0; i < 4; ++i) {
      af[i] = *(const short8*)&As[(wr * 64 + i * 16 + lq) * 32 + hi * 8];
      bf[i] = *(const short8*)&Bs[(wc * 64 + i * 16 + lq) * 32 + hi * 8];
    }
#pragma unroll
    for (int i = 0; i < 4; ++i)
#pragma unroll
      for (int j = 0; j < 4; ++j) acc[i][j] = mfma16(af[i], bf[j], acc[i][j]);
    __syncthreads();
  }

#pragma unroll
  for (int i = 0; i < 4; ++i) {
#pragma unroll
    for (int j = 0; j < 4; ++j) {
      const int mg = m0 + wr * 64 + i * 16 + hi * 4;  // + r
      const int ng = n0 + wc * 64 + j * 16 + lq;
      if (MODE == 0) {
        const int h = ng >> 6, dk = ng & 63;
        u16* o = (u16*)out;
#pragma unroll
        for (int r = 0; r < 4; ++r) {
          int m = mg + r;
          int b = m >> 11, s = m & 2047;
          o[(((size_t)(b * NHEADS + h) * SS + s) << 6) + dk] = f2bf(acc[i][j][r] * oscale);
        }
      } else if (MODE == 1) {
        const int h = ng >> 6, dk = ng & 63;
        const int b = mg >> 11, s = mg & 2047;  // s multiple of 4
        uint2 pk;
        pk.x = (u32)f2bf(acc[i][j][0]) | ((u32)f2bf(acc[i][j][1]) << 16);
        pk.y = (u32)f2bf(acc[i][j][2]) | ((u32)f2bf(acc[i][j][3]) << 16);
        *(uint2*)&((u16*)out)[(((size_t)(b * NHEADS + h) * DK + dk) << 11) + s] = pk;
      } else {
        float* o = (float*)out;
#pragma unroll
        for (int r = 0; r < 4; ++r) o[(size_t)(mg + r) * 1024 + ng] = acc[i][j][r];
      }
    }
  }
}

// ---------------- flash attention, deferred-PV pipeline -------------------
// Qh: [b,h,s,dk] bf16 PRE-SCALED by 0.125*log2e ; Kh: [b,h,s,dk] bf16 ;
// Vt: [b,h,dk,s] bf16 ; out: [b*S+s, h*64+d] bf16
// Block = 512 threads (8 waves), 128 q rows (16 per wave). KVBLK=64.
// Pipeline: step t stages tile t+1, computes QK(t), PV(t-1), softmax(t).
// K tiles: 2 buffers (live [t-1 .. t]); V tiles: 3 buffers (live [t-1 .. t+1]).
// lsum accumulated on the MFMA pipe via a ones-fragment PV (oacc5).
// Raw s_barrier + explicit vmcnt(0); one barrier per step.
__global__ __launch_bounds__(512, 6) void attn_kernel(const u16* __restrict__ Qh,
                                                      const u16* __restrict__ Kh,
                                                      const u16* __restrict__ Vt,
                                                      const int* __restrict__ mask,
                                                      u16* __restrict__ attn_out) {
  __shared__ __align__(16) u16 Ks[2][64 * 64];
  __shared__ __align__(16) u16 Vs[3][64 * 64];
  __shared__ __align__(16) float bias2[SS];
  const int tid = threadIdx.x;
  const int l = tid & 63, w = tid >> 6;
  // bijective XCD-chunk swizzle: 1024 blocks, 8 XCDs, 128 per chunk
  int wg = ((int)blockIdx.x & 7) * 128 + ((int)blockIdx.x >> 3);
  const int qt = wg & 15, h = (wg >> 4) & 15, b = wg >> 8;
  const int lq = l & 15, hi = l >> 4;

  const int* mrow = mask + b * SS;
  for (int i = tid; i < SS; i += 512) bias2[i] = mrow[i] ? 0.0f : -1e13f;

  const size_t bh = (size_t)(b * NHEADS + h);
  const u16* Qp = Qh + bh * ((size_t)SS * DK);
  const u16* Kp = Kh + bh * ((size_t)SS * DK);
  const u16* Vp = Vt + bh * ((size_t)DK * SS);

  const int srow = tid >> 3;
  const int gchunk = (tid & 7) ^ (srow & 7);
  const u16* kg = Kp + (size_t)srow * 64 + gchunk * 8;          // + kv0*64
  const u16* vg = Vp + (size_t)srow * 2048 + gchunk * 8;        // + kv0
  const int ldsbase = w * 512;  // 8 rows * 64 elements per wave

#define STAGEK(buf, kv0)                                                       \
  __builtin_amdgcn_global_load_lds(                                            \
      (const __attribute__((address_space(1))) void*)(kg + (size_t)(kv0)*64),  \
      (__attribute__((address_space(3))) void*)&Ks[buf][ldsbase], 16, 0, 0)
#define STAGEV(buf, kv0)                                                       \
  __builtin_amdgcn_global_load_lds(                                            \
      (const __attribute__((address_space(1))) void*)(vg + (kv0)),             \
      (__attribute__((address_space(3))) void*)&Vs[buf][ldsbase], 16, 0, 0)

  const int q0 = qt * 128 + w * 16;
  short8 qf[2];
#pragma unroll
  for (int kd = 0; kd < 2; ++kd)
    qf[kd] = *(const short8*)&Qp[(q0 + lq) * 64 + kd * 32 + hi * 8];

  const short8 ones8 = {(short)0x3F80, (short)0x3F80, (short)0x3F80, (short)0x3F80,
                        (short)0x3F80, (short)0x3F80, (short)0x3F80, (short)0x3F80};

  f32x4 oacc[4] = {};
  f32x4 oacc5 = {};
  short8 pfA = {}, pfB = {};
  const int rx = lq & 7;
  const int csw = ((hi ^ rx) * 8);  // swizzled chunk -> element offset

  STAGEK(0, 0);
  STAGEV(0, 0);
  __syncthreads();  // drains vmcnt(0) + lgkm (bias2 writes)

  for (int it = 0; it < 32; ++it) {
    const int kv0 = it * 64;
    const int kR = it & 1;
    if (it < 31) {
      STAGEK((it + 1) & 1, kv0 + 64);
      STAGEV((it + 1) % 3, kv0 + 64);
    }

    // QK(it) in exp2 units, bias as C-init
    f32x4 st[4];
    __builtin_amdgcn_s_setprio(1);
#pragma unroll
    for (int t = 0; t < 4; ++t) {
      const u16* kp = &Ks[kR][(t * 16 + lq) * 64 + csw];
      const u16* kp1 = (const u16*)((uintptr_t)kp ^ 64);  // chunk ^4
      f32x4 z = *(const f32x4*)&bias2[kv0 + t * 16 + hi * 4];
      z = mfma16(*(const short8*)kp, qf[0], z);
      z = mfma16(*(const short8*)kp1, qf[1], z);
      st[t] = z;
    }
    // PV(it-1): overlaps the softmax VALU below on the MFMA pipe
    if (it) {
      const int vR = (it + 2) % 3;  // == (it-1) % 3
#pragma unroll
      for (int dt = 0; dt < 4; ++dt) {
        const u16* vp = &Vs[vR][(dt * 16 + lq) * 64 + csw];
        const u16* vp1 = (const u16*)((uintptr_t)vp ^ 64);
        oacc[dt] = mfma16(*(const short8*)vp, pfA, oacc[dt]);
        oacc[dt] = mfma16(*(const short8*)vp1, pfB, oacc[dt]);
      }
      oacc5 = mfma16(ones8, pfA, oacc5);
      oacc5 = mfma16(ones8, pfB, oacc5);
    }
    __builtin_amdgcn_s_setprio(0);

    // softmax(it): p = exp2(score)
    float y[16];
#pragma unroll
    for (int t = 0; t < 4; ++t)
#pragma unroll
      for (int r = 0; r < 4; ++r)
        y[t * 4 + r] = __builtin_amdgcn_exp2f(st[t][r]);

    // pack -> bf16 fragments for next step's PV
    {
      u32 w0 = cvtpk(y[0], y[1]);
      u32 w1 = cvtpk(y[2], y[3]);
      u32 w2 = cvtpk(y[4], y[5]);
      u32 w3 = cvtpk(y[6], y[7]);
      pl32swap(w0, w2);
      pl32swap(w1, w3);
      pl16swap(w0, w2);
      pl16swap(w1, w3);
      uint4 pk = {w0, w1, w2, w3};
      pfA = __builtin_bit_cast(short8, pk);
      u32 x0 = cvtpk(y[8], y[9]);
      u32 x1 = cvtpk(y[10], y[11]);
      u32 x2 = cvtpk(y[12], y[13]);
      u32 x3 = cvtpk(y[14], y[15]);
      pl32swap(x0, x2);
      pl32swap(x1, x3);
      pl16swap(x0, x2);
      pl16swap(x1, x3);
      uint4 pk2 = {x0, x1, x2, x3};
      pfB = __builtin_bit_cast(short8, pk2);
    }

    asm volatile("s_waitcnt vmcnt(0)" ::: "memory");
    __builtin_amdgcn_s_barrier();
  }

  // tail: PV(31) from Vs[31 % 3 == 1]
  {
#pragma unroll
    for (int dt = 0; dt < 4; ++dt) {
      const u16* vp = &Vs[1][(dt * 16 + lq) * 64 + csw];
      const u16* vp1 = (const u16*)((uintptr_t)vp ^ 64);
      oacc[dt] = mfma16(*(const short8*)vp, pfA, oacc[dt]);
      oacc[dt] = mfma16(*(const short8*)vp1, pfB, oacc[dt]);
    }
    oacc5 = mfma16(ones8, pfA, oacc5);
    oacc5 = mfma16(ones8, pfB, oacc5);
  }

  const float inv = 1.0f / oacc5[0];  // all rows/regs of oacc5 equal per lane
  const int q = q0 + lq;
  const size_t obase = (((size_t)(b * SS + q)) << 10) + h * 64;
#pragma unroll
  for (int dt = 0; dt < 4; ++dt) {
    const int dbase = dt * 16 + hi * 4;
    uint2 pk;
    pk.x = (u32)f2bf(oacc[dt][0] * inv) | ((u32)f2bf(oacc[dt][1] * inv) << 16);
    pk.y = (u32)f2bf(oacc[dt][2] * inv) | ((u32)f2bf(oacc[dt][3] * inv) << 16);
    *(uint2*)&attn_out[obase + dbase] = pk;
  }
#undef STAGEK
#undef STAGEV
}

extern "C" void kernel_launch(void* const* d_in, const int* in_sizes, int n_in,
                              void* d_out, int out_size, void* d_ws, size_t ws_size,
                              hipStream_t stream) {
  const float* q_in = (const float*)d_in[0];
  const float* k_in = (const float*)d_in[1];
  const float* v_in = (const float*)d_in[2];
  const int* mask = (const int*)d_in[3];
  const float* Wq = (const float*)d_in[4];
  const float* Wk = (const float*)d_in[5];
  const float* Wv = (const float*)d_in[6];
  const float* Wo = (const float*)d_in[7];

  char* ws = (char*)d_ws;
  const size_t MB = 1ull << 20;
  u16* qb  = (u16*)(ws + 0 * MB);
  u16* kb  = (u16*)(ws + 16 * MB);
  u16* vb  = (u16*)(ws + 32 * MB);
  u16* wqb = (u16*)(ws + 48 * MB);
  u16* wkb = (u16*)(ws + 50 * MB);
  u16* wvb = (u16*)(ws + 52 * MB);
  u16* wob = (u16*)(ws + 54 * MB);
  u16* Qh  = (u16*)(ws + 56 * MB);
  u16* Kh  = (u16*)(ws + 72 * MB);
  u16* Vt  = (u16*)(ws + 88 * MB);
  u16* attn = (u16*)(ws + 104 * MB);  // total 120MB

  const int NX4 = (M_TOT * D_MODEL) / 4;
  const int NW4 = (D_MODEL * D_MODEL) / 4;
  cvt3_kernel<<<dim3(2048, 3), 256, 0, stream>>>(q_in, k_in, v_in, qb, kb, vb, NX4);
  cvt4_kernel<<<dim3(512, 4), 256, 0, stream>>>(Wq, Wk, Wv, Wo, wqb, wkb, wvb, wob, NW4);

  dim3 gg(M_TOT / 128, D_MODEL / 128);
  gemm_bt<0><<<gg, 256, 0, stream>>>(qb, wqb, Qh, QK_SCALE);  // Q pre-scaled
  gemm_bt<0><<<gg, 256, 0, stream>>>(kb, wkb, Kh, 1.0f);
  gemm_bt<1><<<gg, 256, 0, stream>>>(vb, wvb, Vt, 1.0f);

  attn_kernel<<<1024, 512, 0, stream>>>(Qh, Kh, Vt, mask, attn);

  gemm_bt<2><<<gg, 256, 0, stream>>>(attn, wob, d_out, 1.0f);
}

// Round 8
// 210.267 us; speedup vs baseline: 1.1360x; 1.1360x over previous
//
#include <hip/hip_runtime.h>
#include <hip/hip_bf16.h>
#include <stdint.h>

typedef unsigned short u16;
typedef unsigned int u32;

#define D_MODEL 1024
#define NHEADS 16
#define DK 64
#define BB 4
#define SS 2048
#define M_TOT (BB * SS)  // 8192
#define QK_SCALE 0.18033688011112042f  // 0.125 * log2(e)

typedef __attribute__((ext_vector_type(8))) short short8;
typedef __attribute__((ext_vector_type(8))) __bf16 bf16x8;
typedef __attribute__((ext_vector_type(4))) float f32x4;

static __device__ __forceinline__ f32x4 mfma16(short8 a, short8 b, f32x4 c) {
  return __builtin_amdgcn_mfma_f32_16x16x32_bf16(
      __builtin_bit_cast(bf16x8, a), __builtin_bit_cast(bf16x8, b), c, 0, 0, 0);
}

// round-to-nearest-even f32 -> bf16
static __device__ __forceinline__ u16 f2bf(float f) {
  u32 u = __builtin_bit_cast(u32, f);
  u += 0x7fffu + ((u >> 16) & 1u);
  return (u16)(u >> 16);
}

// packed f32x2 -> bf16x2 (RNE); dst.lo = lo, dst.hi = hi
static __device__ __forceinline__ u32 cvtpk(float lo, float hi) {
  u32 r;
  asm("v_cvt_pk_bf16_f32 %0, %1, %2" : "=v"(r) : "v"(lo), "v"(hi));
  return r;
}
// swap a.lanes[32:63] <-> b.lanes[0:31]   (vdst.hi32 <-> vsrc.lo32)
static __device__ __forceinline__ void pl32swap(u32& a, u32& b) {
  asm("v_permlane32_swap_b32 %0, %1" : "+v"(a), "+v"(b));
}
// swap a.odd-16-rows <-> b.even-16-rows
static __device__ __forceinline__ void pl16swap(u32& a, u32& b) {
  asm("v_permlane16_swap_b32 %0, %1" : "+v"(a), "+v"(b));
}

// ---------------- f32 -> bf16 converts (fused launches) ----------------
__global__ void cvt3_kernel(const float* __restrict__ s0, const float* __restrict__ s1,
                            const float* __restrict__ s2, u16* __restrict__ d0,
                            u16* __restrict__ d1, u16* __restrict__ d2, int n4) {
  const float* s = blockIdx.y == 0 ? s0 : blockIdx.y == 1 ? s1 : s2;
  u16* d = blockIdx.y == 0 ? d0 : blockIdx.y == 1 ? d1 : d2;
  int stride = gridDim.x * blockDim.x;
  for (int i = blockIdx.x * blockDim.x + threadIdx.x; i < n4; i += stride) {
    float4 v = reinterpret_cast<const float4*>(s)[i];
    ushort4 o;
    o.x = f2bf(v.x); o.y = f2bf(v.y); o.z = f2bf(v.z); o.w = f2bf(v.w);
    reinterpret_cast<ushort4*>(d)[i] = o;
  }
}
__global__ void cvt4_kernel(const float* __restrict__ s0, const float* __restrict__ s1,
                            const float* __restrict__ s2, const float* __restrict__ s3,
                            u16* __restrict__ d0, u16* __restrict__ d1,
                            u16* __restrict__ d2, u16* __restrict__ d3, int n4) {
  const float* s = blockIdx.y == 0 ? s0 : blockIdx.y == 1 ? s1 : blockIdx.y == 2 ? s2 : s3;
  u16* d = blockIdx.y == 0 ? d0 : blockIdx.y == 1 ? d1 : blockIdx.y == 2 ? d2 : d3;
  int stride = gridDim.x * blockDim.x;
  for (int i = blockIdx.x * blockDim.x + threadIdx.x; i < n4; i += stride) {
    float4 v = reinterpret_cast<const float4*>(s)[i];
    ushort4 o;
    o.x = f2bf(v.x); o.y = f2bf(v.y); o.z = f2bf(v.z); o.w = f2bf(v.w);
    reinterpret_cast<ushort4*>(d)[i] = o;
  }
}

// ------------- fused Q/K/V projection GEMMs (z selects which) -------------
// C[m,n] = sum_k A[m,k]*Bt[n,k]; z=0: ->Qh (bf16 [b,h,s,dk], *QK_SCALE)
// z=1: ->Kh (bf16 [b,h,s,dk]); z=2: ->Vt (bf16 [b,h,dk,s], transposed)
__global__ __launch_bounds__(256, 2) void gemm_qkv(const u16* __restrict__ qb,
                                                   const u16* __restrict__ kb,
                                                   const u16* __restrict__ vb,
                                                   const u16* __restrict__ wqb,
                                                   const u16* __restrict__ wkb,
                                                   const u16* __restrict__ wvb,
                                                   u16* __restrict__ Qh,
                                                   u16* __restrict__ Kh,
                                                   u16* __restrict__ Vt) {
  __shared__ __align__(16) u16 As[128 * 32];
  __shared__ __align__(16) u16 Bs[128 * 32];
  const int z = blockIdx.z;
  const u16* A = z == 0 ? qb : z == 1 ? kb : vb;
  const u16* Bt = z == 0 ? wqb : z == 1 ? wkb : wvb;
  const int tid = threadIdx.x;
  const int l = tid & 63, w = tid >> 6;
  const int m0 = blockIdx.x * 128, n0 = blockIdx.y * 128;
  const int wr = w >> 1, wc = w & 1;
  const int lq = l & 15, hi = l >> 4;

  f32x4 acc[4][4] = {};

  const int row_t = tid >> 2;        // + c*64
  const int col8 = (tid & 3) * 8;

  for (int k0 = 0; k0 < 1024; k0 += 32) {
#pragma unroll
    for (int c = 0; c < 2; ++c) {
      int row = c * 64 + row_t;
      const u16* ga = A + (size_t)(m0 + row) * 1024 + k0 + col8;
      const u16* gb = Bt + (size_t)(n0 + row) * 1024 + k0 + col8;
      __builtin_amdgcn_global_load_lds(
          (const __attribute__((address_space(1))) void*)ga,
          (__attribute__((address_space(3))) void*)&As[(c * 256 + w * 64) * 8], 16, 0, 0);
      __builtin_amdgcn_global_load_lds(
          (const __attribute__((address_space(1))) void*)gb,
          (__attribute__((address_space(3))) void*)&Bs[(c * 256 + w * 64) * 8], 16, 0, 0);
    }
    __syncthreads();
    short8 af[4], bf[4];
#pragma unroll
    for (int i = 0; i < 4; ++i) {
      af[i] = *(const short8*)&As[(wr * 64 + i * 16 + lq) * 32 + hi * 8];
      bf[i] = *(const short8*)&Bs[(wc * 64 + i * 16 + lq) * 32 + hi * 8];
    }
#pragma unroll
    for (int i = 0; i < 4; ++i)
#pragma unroll
      for (int j = 0; j < 4; ++j) acc[i][j] = mfma16(af[i], bf[j], acc[i][j]);
    __syncthreads();
  }

  const float oscale = z == 0 ? QK_SCALE : 1.0f;
#pragma unroll
  for (int i = 0; i < 4; ++i) {
#pragma unroll
    for (int j = 0; j < 4; ++j) {
      const int mg = m0 + wr * 64 + i * 16 + hi * 4;  // + r
      const int ng = n0 + wc * 64 + j * 16 + lq;
      const int h = ng >> 6, dk = ng & 63;
      if (z < 2) {
        u16* o = z == 0 ? Qh : Kh;
#pragma unroll
        for (int r = 0; r < 4; ++r) {
          int m = mg + r;
          int b = m >> 11, s = m & 2047;
          o[(((size_t)(b * NHEADS + h) * SS + s) << 6) + dk] = f2bf(acc[i][j][r] * oscale);
        }
      } else {
        const int b = mg >> 11, s = mg & 2047;  // s multiple of 4
        uint2 pk;
        pk.x = (u32)f2bf(acc[i][j][0]) | ((u32)f2bf(acc[i][j][1]) << 16);
        pk.y = (u32)f2bf(acc[i][j][2]) | ((u32)f2bf(acc[i][j][3]) << 16);
        *(uint2*)&Vt[(((size_t)(b * NHEADS + h) * DK + dk) << 11) + s] = pk;
      }
    }
  }
}

// ---------------- output GEMM: f32 out ----------------
__global__ __launch_bounds__(256, 2) void gemm_out(const u16* __restrict__ A,
                                                   const u16* __restrict__ Bt,
                                                   float* __restrict__ out) {
  __shared__ __align__(16) u16 As[128 * 32];
  __shared__ __align__(16) u16 Bs[128 * 32];
  const int tid = threadIdx.x;
  const int l = tid & 63, w = tid >> 6;
  const int m0 = blockIdx.x * 128, n0 = blockIdx.y * 128;
  const int wr = w >> 1, wc = w & 1;
  const int lq = l & 15, hi = l >> 4;

  f32x4 acc[4][4] = {};

  const int row_t = tid >> 2;
  const int col8 = (tid & 3) * 8;

  for (int k0 = 0; k0 < 1024; k0 += 32) {
#pragma unroll
    for (int c = 0; c < 2; ++c) {
      int row = c * 64 + row_t;
      const u16* ga = A + (size_t)(m0 + row) * 1024 + k0 + col8;
      const u16* gb = Bt + (size_t)(n0 + row) * 1024 + k0 + col8;
      __builtin_amdgcn_global_load_lds(
          (const __attribute__((address_space(1))) void*)ga,
          (__attribute__((address_space(3))) void*)&As[(c * 256 + w * 64) * 8], 16, 0, 0);
      __builtin_amdgcn_global_load_lds(
          (const __attribute__((address_space(1))) void*)gb,
          (__attribute__((address_space(3))) void*)&Bs[(c * 256 + w * 64) * 8], 16, 0, 0);
    }
    __syncthreads();
    short8 af[4], bf[4];
#pragma unroll
    for (int i = 0; i < 4; ++i) {
      af[i] = *(const short8*)&As[(wr * 64 + i * 16 + lq) * 32 + hi * 8];
      bf[i] = *(const short8*)&Bs[(wc * 64 + i * 16 + lq) * 32 + hi * 8];
    }
#pragma unroll
    for (int i = 0; i < 4; ++i)
#pragma unroll
      for (int j = 0; j < 4; ++j) acc[i][j] = mfma16(af[i], bf[j], acc[i][j]);
    __syncthreads();
  }

#pragma unroll
  for (int i = 0; i < 4; ++i)
#pragma unroll
    for (int j = 0; j < 4; ++j) {
      const int mg = m0 + wr * 64 + i * 16 + hi * 4;
      const int ng = n0 + wc * 64 + j * 16 + lq;
#pragma unroll
      for (int r = 0; r < 4; ++r) out[(size_t)(mg + r) * 1024 + ng] = acc[i][j][r];
    }
}

// ------- flash attention, 32 q/wave, fixed-max exp2 softmax ---------------
// Qh: [b,h,s,dk] bf16 PRE-SCALED by 0.125*log2e ; Kh: [b,h,s,dk] bf16 ;
// Vt: [b,h,dk,s] bf16 ; out: [b*S+s, h*64+d] bf16
// Block = 512 threads (8 waves), 256 q rows (32 per wave, 2 groups of 16).
// KVBLK=64, 2-buffer LDS; each K/V fragment read feeds BOTH q-groups
// (halves LDS read traffic per FLOP vs 16 q/wave).
__global__ __launch_bounds__(512, 4) void attn_kernel(const u16* __restrict__ Qh,
                                                      const u16* __restrict__ Kh,
                                                      const u16* __restrict__ Vt,
                                                      const int* __restrict__ mask,
                                                      u16* __restrict__ attn_out) {
  __shared__ __align__(16) u16 Ks[2][64 * 64];
  __shared__ __align__(16) u16 Vs[2][64 * 64];
  __shared__ __align__(16) float bias2[SS];
  const int tid = threadIdx.x;
  const int l = tid & 63, w = tid >> 6;
  // bijective XCD-chunk swizzle: 512 blocks, 8 XCDs, 64 per chunk
  int wg = ((int)blockIdx.x & 7) * 64 + ((int)blockIdx.x >> 3);
  const int qt = wg & 7, h = (wg >> 3) & 15, b = wg >> 7;
  const int lq = l & 15, hi = l >> 4;

  const int* mrow = mask + b * SS;
  for (int i = tid; i < SS; i += 512) bias2[i] = mrow[i] ? 0.0f : -1e13f;

  const size_t bh = (size_t)(b * NHEADS + h);
  const u16* Qp = Qh + bh * ((size_t)SS * DK);
  const u16* Kp = Kh + bh * ((size_t)SS * DK);
  const u16* Vp = Vt + bh * ((size_t)DK * SS);

  const int srow = tid >> 3;
  const int gchunk = (tid & 7) ^ (srow & 7);
  const u16* kg = Kp + (size_t)srow * 64 + gchunk * 8;          // + kv0*64
  const u16* vg = Vp + (size_t)srow * 2048 + gchunk * 8;        // + kv0
  const int ldsbase = w * 512;  // 8 rows * 64 elements per wave

#define STAGE(buf, kv0)                                                        \
  do {                                                                         \
    __builtin_amdgcn_global_load_lds(                                          \
        (const __attribute__((address_space(1))) void*)(kg + (size_t)(kv0)*64),\
        (__attribute__((address_space(3))) void*)&Ks[buf][ldsbase], 16, 0, 0); \
    __builtin_amdgcn_global_load_lds(                                          \
        (const __attribute__((address_space(1))) void*)(vg + (kv0)),           \
        (__attribute__((address_space(3))) void*)&Vs[buf][ldsbase], 16, 0, 0); \
  } while (0)

  const int q0 = qt * 256 + w * 32;
  short8 qf[2][2];
#pragma unroll
  for (int qg = 0; qg < 2; ++qg)
#pragma unroll
    for (int kd = 0; kd < 2; ++kd)
      qf[qg][kd] = *(const short8*)&Qp[(q0 + qg * 16 + lq) * 64 + kd * 32 + hi * 8];

  f32x4 oacc[2][4] = {};
  f32x4 psv[2] = {};
  const int rx = lq & 7;
  const int csw = ((hi ^ rx) * 8);  // swizzled chunk -> element offset

  STAGE(0, 0);
  __syncthreads();
  int cur = 0;

  for (int it = 0; it < 32; ++it) {
    const int kv0 = it * 64;
    if (it < 31) STAGE(cur ^ 1, kv0 + 64);

    // QK both groups: K frags read once, reused for qg=0,1
    f32x4 st[2][4];
    __builtin_amdgcn_s_setprio(1);
#pragma unroll
    for (int t = 0; t < 4; ++t) {
      const u16* kp = &Ks[cur][(t * 16 + lq) * 64 + csw];
      short8 kf0 = *(const short8*)kp;
      short8 kf1 = *(const short8*)((uintptr_t)kp ^ 64);  // chunk ^4
      f32x4 bz = *(const f32x4*)&bias2[kv0 + t * 16 + hi * 4];
#pragma unroll
      for (int qg = 0; qg < 2; ++qg) {
        f32x4 zz = mfma16(kf0, qf[qg][0], bz);
        st[qg][t] = mfma16(kf1, qf[qg][1], zz);
      }
    }
    __builtin_amdgcn_s_setprio(0);

    // softmax + pack per group (exp2 fused into cvtpk inputs)
    short8 pfA[2], pfB[2];
#pragma unroll
    for (int qg = 0; qg < 2; ++qg) {
      u32 wd[4];
#pragma unroll
      for (int t2 = 0; t2 < 2; ++t2)
#pragma unroll
        for (int p = 0; p < 2; ++p) {
          float plo = __builtin_amdgcn_exp2f(st[qg][t2][2 * p]);
          float phi = __builtin_amdgcn_exp2f(st[qg][t2][2 * p + 1]);
          psv[qg][2 * p] += plo;
          psv[qg][2 * p + 1] += phi;
          wd[t2 * 2 + p] = cvtpk(plo, phi);
        }
      u32 xd[4];
#pragma unroll
      for (int t2 = 0; t2 < 2; ++t2)
#pragma unroll
        for (int p = 0; p < 2; ++p) {
          float plo = __builtin_amdgcn_exp2f(st[qg][2 + t2][2 * p]);
          float phi = __builtin_amdgcn_exp2f(st[qg][2 + t2][2 * p + 1]);
          psv[qg][2 * p] += plo;
          psv[qg][2 * p + 1] += phi;
          xd[t2 * 2 + p] = cvtpk(plo, phi);
        }
      pl32swap(wd[0], wd[2]);
      pl32swap(wd[1], wd[3]);
      pl16swap(wd[0], wd[2]);
      pl16swap(wd[1], wd[3]);
      uint4 pk = {wd[0], wd[1], wd[2], wd[3]};
      pfA[qg] = __builtin_bit_cast(short8, pk);
      pl32swap(xd[0], xd[2]);
      pl32swap(xd[1], xd[3]);
      pl16swap(xd[0], xd[2]);
      pl16swap(xd[1], xd[3]);
      uint4 pk2 = {xd[0], xd[1], xd[2], xd[3]};
      pfB[qg] = __builtin_bit_cast(short8, pk2);
    }

    // PV both groups: V frags read once, reused for qg=0,1
    __builtin_amdgcn_s_setprio(1);
#pragma unroll
    for (int dt = 0; dt < 4; ++dt) {
      const u16* vp = &Vs[cur][(dt * 16 + lq) * 64 + csw];
      short8 vf0 = *(const short8*)vp;
      short8 vf1 = *(const short8*)((uintptr_t)vp ^ 64);
#pragma unroll
      for (int qg = 0; qg < 2; ++qg) {
        oacc[qg][dt] = mfma16(vf0, pfA[qg], oacc[qg][dt]);
        oacc[qg][dt] = mfma16(vf1, pfB[qg], oacc[qg][dt]);
      }
    }
    __builtin_amdgcn_s_setprio(0);
    __syncthreads();
    cur ^= 1;
  }

#pragma unroll
  for (int qg = 0; qg < 2; ++qg) {
    float lsum = psv[qg][0] + psv[qg][1] + psv[qg][2] + psv[qg][3];
    lsum += __shfl_xor(lsum, 16);
    lsum += __shfl_xor(lsum, 32);
    const float inv = 1.0f / lsum;
    const int q = q0 + qg * 16 + lq;
    const size_t obase = (((size_t)(b * SS + q)) << 10) + h * 64;
#pragma unroll
    for (int dt = 0; dt < 4; ++dt) {
      const int dbase = dt * 16 + hi * 4;
      uint2 pk;
      pk.x = (u32)f2bf(oacc[qg][dt][0] * inv) | ((u32)f2bf(oacc[qg][dt][1] * inv) << 16);
      pk.y = (u32)f2bf(oacc[qg][dt][2] * inv) | ((u32)f2bf(oacc[qg][dt][3] * inv) << 16);
      *(uint2*)&attn_out[obase + dbase] = pk;
    }
  }
#undef STAGE
}

extern "C" void kernel_launch(void* const* d_in, const int* in_sizes, int n_in,
                              void* d_out, int out_size, void* d_ws, size_t ws_size,
                              hipStream_t stream) {
  const float* q_in = (const float*)d_in[0];
  const float* k_in = (const float*)d_in[1];
  const float* v_in = (const float*)d_in[2];
  const int* mask = (const int*)d_in[3];
  const float* Wq = (const float*)d_in[4];
  const float* Wk = (const float*)d_in[5];
  const float* Wv = (const float*)d_in[6];
  const float* Wo = (const float*)d_in[7];

  char* ws = (char*)d_ws;
  const size_t MB = 1ull << 20;
  u16* qb  = (u16*)(ws + 0 * MB);
  u16* kb  = (u16*)(ws + 16 * MB);
  u16* vb  = (u16*)(ws + 32 * MB);
  u16* wqb = (u16*)(ws + 48 * MB);
  u16* wkb = (u16*)(ws + 50 * MB);
  u16* wvb = (u16*)(ws + 52 * MB);
  u16* wob = (u16*)(ws + 54 * MB);
  u16* Qh  = (u16*)(ws + 56 * MB);
  u16* Kh  = (u16*)(ws + 72 * MB);
  u16* Vt  = (u16*)(ws + 88 * MB);
  u16* attn = (u16*)(ws + 104 * MB);  // total 120MB

  const int NX4 = (M_TOT * D_MODEL) / 4;
  const int NW4 = (D_MODEL * D_MODEL) / 4;
  cvt3_kernel<<<dim3(2048, 3), 256, 0, stream>>>(q_in, k_in, v_in, qb, kb, vb, NX4);
  cvt4_kernel<<<dim3(512, 4), 256, 0, stream>>>(Wq, Wk, Wv, Wo, wqb, wkb, wvb, wob, NW4);

  gemm_qkv<<<dim3(M_TOT / 128, D_MODEL / 128, 3), 256, 0, stream>>>(
      qb, kb, vb, wqb, wkb, wvb, Qh, Kh, Vt);

  attn_kernel<<<512, 512, 0, stream>>>(Qh, Kh, Vt, mask, attn);

  gemm_out<<<dim3(M_TOT / 128, D_MODEL / 128), 256, 0, stream>>>(attn, wob, (float*)d_out);
}

// Round 9
// 209.634 us; speedup vs baseline: 1.1394x; 1.0030x over previous
//
#include <hip/hip_runtime.h>
#include <hip/hip_bf16.h>
#include <stdint.h>

typedef unsigned short u16;
typedef unsigned int u32;

#define D_MODEL 1024
#define NHEADS 16
#define DK 64
#define BB 4
#define SS 2048
#define M_TOT (BB * SS)  // 8192
#define QK_SCALE 0.18033688011112042f  // 0.125 * log2(e)

typedef __attribute__((ext_vector_type(8))) short short8;
typedef __attribute__((ext_vector_type(8))) __bf16 bf16x8;
typedef __attribute__((ext_vector_type(4))) float f32x4;

static __device__ __forceinline__ f32x4 mfma16(short8 a, short8 b, f32x4 c) {
  return __builtin_amdgcn_mfma_f32_16x16x32_bf16(
      __builtin_bit_cast(bf16x8, a), __builtin_bit_cast(bf16x8, b), c, 0, 0, 0);
}

// round-to-nearest-even f32 -> bf16
static __device__ __forceinline__ u16 f2bf(float f) {
  u32 u = __builtin_bit_cast(u32, f);
  u += 0x7fffu + ((u >> 16) & 1u);
  return (u16)(u >> 16);
}

// packed f32x2 -> bf16x2 (RNE); dst.lo = lo, dst.hi = hi
static __device__ __forceinline__ u32 cvtpk(float lo, float hi) {
  u32 r;
  asm("v_cvt_pk_bf16_f32 %0, %1, %2" : "=v"(r) : "v"(lo), "v"(hi));
  return r;
}
// swap a.lanes[32:63] <-> b.lanes[0:31]   (vdst.hi32 <-> vsrc.lo32)
static __device__ __forceinline__ void pl32swap(u32& a, u32& b) {
  asm("v_permlane32_swap_b32 %0, %1" : "+v"(a), "+v"(b));
}
// swap a.odd-16-rows <-> b.even-16-rows
static __device__ __forceinline__ void pl16swap(u32& a, u32& b) {
  asm("v_permlane16_swap_b32 %0, %1" : "+v"(a), "+v"(b));
}

// ---------------- f32 -> bf16 converts (fused launches) ----------------
__global__ void cvt3_kernel(const float* __restrict__ s0, const float* __restrict__ s1,
                            const float* __restrict__ s2, u16* __restrict__ d0,
                            u16* __restrict__ d1, u16* __restrict__ d2, int n4) {
  const float* s = blockIdx.y == 0 ? s0 : blockIdx.y == 1 ? s1 : s2;
  u16* d = blockIdx.y == 0 ? d0 : blockIdx.y == 1 ? d1 : d2;
  int stride = gridDim.x * blockDim.x;
  for (int i = blockIdx.x * blockDim.x + threadIdx.x; i < n4; i += stride) {
    float4 v = reinterpret_cast<const float4*>(s)[i];
    ushort4 o;
    o.x = f2bf(v.x); o.y = f2bf(v.y); o.z = f2bf(v.z); o.w = f2bf(v.w);
    reinterpret_cast<ushort4*>(d)[i] = o;
  }
}
__global__ void cvt4_kernel(const float* __restrict__ s0, const float* __restrict__ s1,
                            const float* __restrict__ s2, const float* __restrict__ s3,
                            u16* __restrict__ d0, u16* __restrict__ d1,
                            u16* __restrict__ d2, u16* __restrict__ d3, int n4) {
  const float* s = blockIdx.y == 0 ? s0 : blockIdx.y == 1 ? s1 : blockIdx.y == 2 ? s2 : s3;
  u16* d = blockIdx.y == 0 ? d0 : blockIdx.y == 1 ? d1 : blockIdx.y == 2 ? d2 : d3;
  int stride = gridDim.x * blockDim.x;
  for (int i = blockIdx.x * blockDim.x + threadIdx.x; i < n4; i += stride) {
    float4 v = reinterpret_cast<const float4*>(s)[i];
    ushort4 o;
    o.x = f2bf(v.x); o.y = f2bf(v.y); o.z = f2bf(v.z); o.w = f2bf(v.w);
    reinterpret_cast<ushort4*>(d)[i] = o;
  }
}

// ------------- fused Q/K/V projection GEMMs (z selects which) -------------
// C[m,n] = sum_k A[m,k]*Bt[n,k]; z=0: ->Qh (bf16 [b,h,s,dk], *QK_SCALE)
// z=1: ->Kh (bf16 [b,h,s,dk]); z=2: ->Vt (bf16 [b,h,dk,s], transposed)
__global__ __launch_bounds__(256, 2) void gemm_qkv(const u16* __restrict__ qb,
                                                   const u16* __restrict__ kb,
                                                   const u16* __restrict__ vb,
                                                   const u16* __restrict__ wqb,
                                                   const u16* __restrict__ wkb,
                                                   const u16* __restrict__ wvb,
                                                   u16* __restrict__ Qh,
                                                   u16* __restrict__ Kh,
                                                   u16* __restrict__ Vt) {
  __shared__ __align__(16) u16 As[128 * 32];
  __shared__ __align__(16) u16 Bs[128 * 32];
  const int z = blockIdx.z;
  const u16* A = z == 0 ? qb : z == 1 ? kb : vb;
  const u16* Bt = z == 0 ? wqb : z == 1 ? wkb : wvb;
  const int tid = threadIdx.x;
  const int l = tid & 63, w = tid >> 6;
  const int m0 = blockIdx.x * 128, n0 = blockIdx.y * 128;
  const int wr = w >> 1, wc = w & 1;
  const int lq = l & 15, hi = l >> 4;

  f32x4 acc[4][4] = {};

  const int row_t = tid >> 2;        // + c*64
  const int col8 = (tid & 3) * 8;

  for (int k0 = 0; k0 < 1024; k0 += 32) {
#pragma unroll
    for (int c = 0; c < 2; ++c) {
      int row = c * 64 + row_t;
      const u16* ga = A + (size_t)(m0 + row) * 1024 + k0 + col8;
      const u16* gb = Bt + (size_t)(n0 + row) * 1024 + k0 + col8;
      __builtin_amdgcn_global_load_lds(
          (const __attribute__((address_space(1))) void*)ga,
          (__attribute__((address_space(3))) void*)&As[(c * 256 + w * 64) * 8], 16, 0, 0);
      __builtin_amdgcn_global_load_lds(
          (const __attribute__((address_space(1))) void*)gb,
          (__attribute__((address_space(3))) void*)&Bs[(c * 256 + w * 64) * 8], 16, 0, 0);
    }
    __syncthreads();
    short8 af[4], bf[4];
#pragma unroll
    for (int i = 0; i < 4; ++i) {
      af[i] = *(const short8*)&As[(wr * 64 + i * 16 + lq) * 32 + hi * 8];
      bf[i] = *(const short8*)&Bs[(wc * 64 + i * 16 + lq) * 32 + hi * 8];
    }
#pragma unroll
    for (int i = 0; i < 4; ++i)
#pragma unroll
      for (int j = 0; j < 4; ++j) acc[i][j] = mfma16(af[i], bf[j], acc[i][j]);
    __syncthreads();
  }

  const float oscale = z == 0 ? QK_SCALE : 1.0f;
#pragma unroll
  for (int i = 0; i < 4; ++i) {
#pragma unroll
    for (int j = 0; j < 4; ++j) {
      const int mg = m0 + wr * 64 + i * 16 + hi * 4;  // + r
      const int ng = n0 + wc * 64 + j * 16 + lq;
      const int h = ng >> 6, dk = ng & 63;
      if (z < 2) {
        u16* o = z == 0 ? Qh : Kh;
#pragma unroll
        for (int r = 0; r < 4; ++r) {
          int m = mg + r;
          int b = m >> 11, s = m & 2047;
          o[(((size_t)(b * NHEADS + h) * SS + s) << 6) + dk] = f2bf(acc[i][j][r] * oscale);
        }
      } else {
        const int b = mg >> 11, s = mg & 2047;  // s multiple of 4
        uint2 pk;
        pk.x = (u32)f2bf(acc[i][j][0]) | ((u32)f2bf(acc[i][j][1]) << 16);
        pk.y = (u32)f2bf(acc[i][j][2]) | ((u32)f2bf(acc[i][j][3]) << 16);
        *(uint2*)&Vt[(((size_t)(b * NHEADS + h) * DK + dk) << 11) + s] = pk;
      }
    }
  }
}

// ---------------- output GEMM: f32 out ----------------
__global__ __launch_bounds__(256, 2) void gemm_out(const u16* __restrict__ A,
                                                   const u16* __restrict__ Bt,
                                                   float* __restrict__ out) {
  __shared__ __align__(16) u16 As[128 * 32];
  __shared__ __align__(16) u16 Bs[128 * 32];
  const int tid = threadIdx.x;
  const int l = tid & 63, w = tid >> 6;
  const int m0 = blockIdx.x * 128, n0 = blockIdx.y * 128;
  const int wr = w >> 1, wc = w & 1;
  const int lq = l & 15, hi = l >> 4;

  f32x4 acc[4][4] = {};

  const int row_t = tid >> 2;
  const int col8 = (tid & 3) * 8;

  for (int k0 = 0; k0 < 1024; k0 += 32) {
#pragma unroll
    for (int c = 0; c < 2; ++c) {
      int row = c * 64 + row_t;
      const u16* ga = A + (size_t)(m0 + row) * 1024 + k0 + col8;
      const u16* gb = Bt + (size_t)(n0 + row) * 1024 + k0 + col8;
      __builtin_amdgcn_global_load_lds(
          (const __attribute__((address_space(1))) void*)ga,
          (__attribute__((address_space(3))) void*)&As[(c * 256 + w * 64) * 8], 16, 0, 0);
      __builtin_amdgcn_global_load_lds(
          (const __attribute__((address_space(1))) void*)gb,
          (__attribute__((address_space(3))) void*)&Bs[(c * 256 + w * 64) * 8], 16, 0, 0);
    }
    __syncthreads();
    short8 af[4], bf[4];
#pragma unroll
    for (int i = 0; i < 4; ++i) {
      af[i] = *(const short8*)&As[(wr * 64 + i * 16 + lq) * 32 + hi * 8];
      bf[i] = *(const short8*)&Bs[(wc * 64 + i * 16 + lq) * 32 + hi * 8];
    }
#pragma unroll
    for (int i = 0; i < 4; ++i)
#pragma unroll
      for (int j = 0; j < 4; ++j) acc[i][j] = mfma16(af[i], bf[j], acc[i][j]);
    __syncthreads();
  }

#pragma unroll
  for (int i = 0; i < 4; ++i)
#pragma unroll
    for (int j = 0; j < 4; ++j) {
      const int mg = m0 + wr * 64 + i * 16 + hi * 4;
      const int ng = n0 + wc * 64 + j * 16 + lq;
#pragma unroll
      for (int r = 0; r < 4; ++r) out[(size_t)(mg + r) * 1024 + ng] = acc[i][j][r];
    }
}

// ------- flash attention, 4-wave blocks for phase diversity ---------------
// Qh: [b,h,s,dk] bf16 PRE-SCALED by 0.125*log2e ; Kh: [b,h,s,dk] bf16 ;
// Vt: [b,h,dk,s] bf16 ; out: [b*S+s, h*64+d] bf16
// Block = 256 threads (4 waves), 128 q rows (32 per wave, 2 groups of 16).
// Grid = 1024 -> 4 blocks/CU (LDS 40960B x4 = 160KiB exactly). Each SIMD
// hosts waves from 4 independent barrier domains -> MFMA/VALU phase overlap.
__global__ __launch_bounds__(256, 4) void attn_kernel(const u16* __restrict__ Qh,
                                                      const u16* __restrict__ Kh,
                                                      const u16* __restrict__ Vt,
                                                      const int* __restrict__ mask,
                                                      u16* __restrict__ attn_out) {
  __shared__ __align__(16) u16 Ks[2][64 * 64];
  __shared__ __align__(16) u16 Vs[2][64 * 64];
  __shared__ __align__(16) float bias2[SS];
  const int tid = threadIdx.x;
  const int l = tid & 63, w = tid >> 6;  // w in 0..3
  // bijective XCD-chunk swizzle: 1024 blocks, 8 XCDs, 128 per chunk
  int wg = ((int)blockIdx.x & 7) * 128 + ((int)blockIdx.x >> 3);
  const int qt = wg & 15, h = (wg >> 4) & 15, b = wg >> 8;
  const int lq = l & 15, hi = l >> 4;

  const int* mrow = mask + b * SS;
  for (int i = tid; i < SS; i += 256) bias2[i] = mrow[i] ? 0.0f : -1e13f;

  const size_t bh = (size_t)(b * NHEADS + h);
  const u16* Qp = Qh + bh * ((size_t)SS * DK);
  const u16* Kp = Kh + bh * ((size_t)SS * DK);
  const u16* Vp = Vt + bh * ((size_t)DK * SS);

  // staging: 256 threads x 2 insts x 16B cover a 64x64 bf16 tile.
  // inst0: rows 0..31 (row = tid>>3), inst1: rows 32..63 (same row&7 -> same
  // source chunk xor). physical chunk = tid&7, logical chunk = (tid&7)^(row&7).
  const int srow = tid >> 3;
  const int gchunk = (tid & 7) ^ (srow & 7);
  const u16* kg = Kp + (size_t)srow * 64 + gchunk * 8;          // + kv0*64
  const u16* vg = Vp + (size_t)srow * 2048 + gchunk * 8;        // + kv0
  const int ldsbase = w * 512;  // 8 rows * 64 elements per wave (inst0)

#define STAGE(buf, kv0)                                                         \
  do {                                                                          \
    __builtin_amdgcn_global_load_lds(                                           \
        (const __attribute__((address_space(1))) void*)(kg + (size_t)(kv0)*64), \
        (__attribute__((address_space(3))) void*)&Ks[buf][ldsbase], 16, 0, 0);  \
    __builtin_amdgcn_global_load_lds(                                           \
        (const __attribute__((address_space(1))) void*)(kg + (size_t)(kv0)*64 + \
                                                        32 * 64),               \
        (__attribute__((address_space(3))) void*)&Ks[buf][2048 + ldsbase], 16,  \
        0, 0);                                                                  \
    __builtin_amdgcn_global_load_lds(                                           \
        (const __attribute__((address_space(1))) void*)(vg + (kv0)),            \
        (__attribute__((address_space(3))) void*)&Vs[buf][ldsbase], 16, 0, 0);  \
    __builtin_amdgcn_global_load_lds(                                           \
        (const __attribute__((address_space(1))) void*)(vg + (kv0) + 32 * 2048),\
        (__attribute__((address_space(3))) void*)&Vs[buf][2048 + ldsbase], 16,  \
        0, 0);                                                                  \
  } while (0)

  const int q0 = qt * 128 + w * 32;
  short8 qf[2][2];
#pragma unroll
  for (int qg = 0; qg < 2; ++qg)
#pragma unroll
    for (int kd = 0; kd < 2; ++kd)
      qf[qg][kd] = *(const short8*)&Qp[(q0 + qg * 16 + lq) * 64 + kd * 32 + hi * 8];

  f32x4 oacc[2][4] = {};
  f32x4 psv[2] = {};
  const int rx = lq & 7;
  const int csw = ((hi ^ rx) * 8);  // swizzled chunk -> element offset

  STAGE(0, 0);
  __syncthreads();
  int cur = 0;

  for (int it = 0; it < 32; ++it) {
    const int kv0 = it * 64;
    if (it < 31) STAGE(cur ^ 1, kv0 + 64);

    // QK both groups: K frags read once, reused for qg=0,1
    f32x4 st[2][4];
    __builtin_amdgcn_s_setprio(1);
#pragma unroll
    for (int t = 0; t < 4; ++t) {
      const u16* kp = &Ks[cur][(t * 16 + lq) * 64 + csw];
      short8 kf0 = *(const short8*)kp;
      short8 kf1 = *(const short8*)((uintptr_t)kp ^ 64);  // chunk ^4
      f32x4 bz = *(const f32x4*)&bias2[kv0 + t * 16 + hi * 4];
#pragma unroll
      for (int qg = 0; qg < 2; ++qg) {
        f32x4 zz = mfma16(kf0, qf[qg][0], bz);
        st[qg][t] = mfma16(kf1, qf[qg][1], zz);
      }
    }
    __builtin_amdgcn_s_setprio(0);

    // softmax + pack per group (exp2 fused into cvtpk inputs)
    short8 pfA[2], pfB[2];
#pragma unroll
    for (int qg = 0; qg < 2; ++qg) {
      u32 wd[4];
#pragma unroll
      for (int t2 = 0; t2 < 2; ++t2)
#pragma unroll
        for (int p = 0; p < 2; ++p) {
          float plo = __builtin_amdgcn_exp2f(st[qg][t2][2 * p]);
          float phi = __builtin_amdgcn_exp2f(st[qg][t2][2 * p + 1]);
          psv[qg][2 * p] += plo;
          psv[qg][2 * p + 1] += phi;
          wd[t2 * 2 + p] = cvtpk(plo, phi);
        }
      u32 xd[4];
#pragma unroll
      for (int t2 = 0; t2 < 2; ++t2)
#pragma unroll
        for (int p = 0; p < 2; ++p) {
          float plo = __builtin_amdgcn_exp2f(st[qg][2 + t2][2 * p]);
          float phi = __builtin_amdgcn_exp2f(st[qg][2 + t2][2 * p + 1]);
          psv[qg][2 * p] += plo;
          psv[qg][2 * p + 1] += phi;
          xd[t2 * 2 + p] = cvtpk(plo, phi);
        }
      pl32swap(wd[0], wd[2]);
      pl32swap(wd[1], wd[3]);
      pl16swap(wd[0], wd[2]);
      pl16swap(wd[1], wd[3]);
      uint4 pk = {wd[0], wd[1], wd[2], wd[3]};
      pfA[qg] = __builtin_bit_cast(short8, pk);
      pl32swap(xd[0], xd[2]);
      pl32swap(xd[1], xd[3]);
      pl16swap(xd[0], xd[2]);
      pl16swap(xd[1], xd[3]);
      uint4 pk2 = {xd[0], xd[1], xd[2], xd[3]};
      pfB[qg] = __builtin_bit_cast(short8, pk2);
    }

    // PV both groups: V frags read once, reused for qg=0,1
    __builtin_amdgcn_s_setprio(1);
#pragma unroll
    for (int dt = 0; dt < 4; ++dt) {
      const u16* vp = &Vs[cur][(dt * 16 + lq) * 64 + csw];
      short8 vf0 = *(const short8*)vp;
      short8 vf1 = *(const short8*)((uintptr_t)vp ^ 64);
#pragma unroll
      for (int qg = 0; qg < 2; ++qg) {
        oacc[qg][dt] = mfma16(vf0, pfA[qg], oacc[qg][dt]);
        oacc[qg][dt] = mfma16(vf1, pfB[qg], oacc[qg][dt]);
      }
    }
    __builtin_amdgcn_s_setprio(0);
    __syncthreads();
    cur ^= 1;
  }

#pragma unroll
  for (int qg = 0; qg < 2; ++qg) {
    float lsum = psv[qg][0] + psv[qg][1] + psv[qg][2] + psv[qg][3];
    lsum += __shfl_xor(lsum, 16);
    lsum += __shfl_xor(lsum, 32);
    const float inv = 1.0f / lsum;
    const int q = q0 + qg * 16 + lq;
    const size_t obase = (((size_t)(b * SS + q)) << 10) + h * 64;
#pragma unroll
    for (int dt = 0; dt < 4; ++dt) {
      const int dbase = dt * 16 + hi * 4;
      uint2 pk;
      pk.x = (u32)f2bf(oacc[qg][dt][0] * inv) | ((u32)f2bf(oacc[qg][dt][1] * inv) << 16);
      pk.y = (u32)f2bf(oacc[qg][dt][2] * inv) | ((u32)f2bf(oacc[qg][dt][3] * inv) << 16);
      *(uint2*)&attn_out[obase + dbase] = pk;
    }
  }
#undef STAGE
}

extern "C" void kernel_launch(void* const* d_in, const int* in_sizes, int n_in,
                              void* d_out, int out_size, void* d_ws, size_t ws_size,
                              hipStream_t stream) {
  const float* q_in = (const float*)d_in[0];
  const float* k_in = (const float*)d_in[1];
  const float* v_in = (const float*)d_in[2];
  const int* mask = (const int*)d_in[3];
  const float* Wq = (const float*)d_in[4];
  const float* Wk = (const float*)d_in[5];
  const float* Wv = (const float*)d_in[6];
  const float* Wo = (const float*)d_in[7];

  char* ws = (char*)d_ws;
  const size_t MB = 1ull << 20;
  u16* qb  = (u16*)(ws + 0 * MB);
  u16* kb  = (u16*)(ws + 16 * MB);
  u16* vb  = (u16*)(ws + 32 * MB);
  u16* wqb = (u16*)(ws + 48 * MB);
  u16* wkb = (u16*)(ws + 50 * MB);
  u16* wvb = (u16*)(ws + 52 * MB);
  u16* wob = (u16*)(ws + 54 * MB);
  u16* Qh  = (u16*)(ws + 56 * MB);
  u16* Kh  = (u16*)(ws + 72 * MB);
  u16* Vt  = (u16*)(ws + 88 * MB);
  u16* attn = (u16*)(ws + 104 * MB);  // total 120MB

  const int NX4 = (M_TOT * D_MODEL) / 4;
  const int NW4 = (D_MODEL * D_MODEL) / 4;
  cvt3_kernel<<<dim3(2048, 3), 256, 0, stream>>>(q_in, k_in, v_in, qb, kb, vb, NX4);
  cvt4_kernel<<<dim3(512, 4), 256, 0, stream>>>(Wq, Wk, Wv, Wo, wqb, wkb, wvb, wob, NW4);

  gemm_qkv<<<dim3(M_TOT / 128, D_MODEL / 128, 3), 256, 0, stream>>>(
      qb, kb, vb, wqb, wkb, wvb, Qh, Kh, Vt);

  attn_kernel<<<1024, 256, 0, stream>>>(Qh, Kh, Vt, mask, attn);

  gemm_out<<<dim3(M_TOT / 128, D_MODEL / 128), 256, 0, stream>>>(attn, wob, (float*)d_out);
}

// Round 10
// 209.260 us; speedup vs baseline: 1.1415x; 1.0018x over previous
//
#include <hip/hip_runtime.h>
#include <hip/hip_bf16.h>
#include <stdint.h>

typedef unsigned short u16;
typedef unsigned int u32;

#define D_MODEL 1024
#define NHEADS 16
#define DK 64
#define BB 4
#define SS 2048
#define M_TOT (BB * SS)  // 8192
#define QK_SCALE 0.18033688011112042f  // 0.125 * log2(e)

typedef __attribute__((ext_vector_type(8))) short short8;
typedef __attribute__((ext_vector_type(8))) __bf16 bf16x8;
typedef __attribute__((ext_vector_type(4))) float f32x4;

static __device__ __forceinline__ f32x4 mfma16(short8 a, short8 b, f32x4 c) {
  return __builtin_amdgcn_mfma_f32_16x16x32_bf16(
      __builtin_bit_cast(bf16x8, a), __builtin_bit_cast(bf16x8, b), c, 0, 0, 0);
}

// round-to-nearest-even f32 -> bf16
static __device__ __forceinline__ u16 f2bf(float f) {
  u32 u = __builtin_bit_cast(u32, f);
  u += 0x7fffu + ((u >> 16) & 1u);
  return (u16)(u >> 16);
}

// packed f32x2 -> bf16x2 (RNE); dst.lo = lo, dst.hi = hi
static __device__ __forceinline__ u32 cvtpk(float lo, float hi) {
  u32 r;
  asm("v_cvt_pk_bf16_f32 %0, %1, %2" : "=v"(r) : "v"(lo), "v"(hi));
  return r;
}
// swap a.lanes[32:63] <-> b.lanes[0:31]   (vdst.hi32 <-> vsrc.lo32)
static __device__ __forceinline__ void pl32swap(u32& a, u32& b) {
  asm("v_permlane32_swap_b32 %0, %1" : "+v"(a), "+v"(b));
}
// swap a.odd-16-rows <-> b.even-16-rows
static __device__ __forceinline__ void pl16swap(u32& a, u32& b) {
  asm("v_permlane16_swap_b32 %0, %1" : "+v"(a), "+v"(b));
}

// ---------------- f32 -> bf16 converts (fused launches) ----------------
__global__ void cvt3_kernel(const float* __restrict__ s0, const float* __restrict__ s1,
                            const float* __restrict__ s2, u16* __restrict__ d0,
                            u16* __restrict__ d1, u16* __restrict__ d2, int n4) {
  const float* s = blockIdx.y == 0 ? s0 : blockIdx.y == 1 ? s1 : s2;
  u16* d = blockIdx.y == 0 ? d0 : blockIdx.y == 1 ? d1 : d2;
  int stride = gridDim.x * blockDim.x;
  for (int i = blockIdx.x * blockDim.x + threadIdx.x; i < n4; i += stride) {
    float4 v = reinterpret_cast<const float4*>(s)[i];
    ushort4 o;
    o.x = f2bf(v.x); o.y = f2bf(v.y); o.z = f2bf(v.z); o.w = f2bf(v.w);
    reinterpret_cast<ushort4*>(d)[i] = o;
  }
}
__global__ void cvt4_kernel(const float* __restrict__ s0, const float* __restrict__ s1,
                            const float* __restrict__ s2, const float* __restrict__ s3,
                            u16* __restrict__ d0, u16* __restrict__ d1,
                            u16* __restrict__ d2, u16* __restrict__ d3, int n4) {
  const float* s = blockIdx.y == 0 ? s0 : blockIdx.y == 1 ? s1 : blockIdx.y == 2 ? s2 : s3;
  u16* d = blockIdx.y == 0 ? d0 : blockIdx.y == 1 ? d1 : blockIdx.y == 2 ? d2 : d3;
  int stride = gridDim.x * blockDim.x;
  for (int i = blockIdx.x * blockDim.x + threadIdx.x; i < n4; i += stride) {
    float4 v = reinterpret_cast<const float4*>(s)[i];
    ushort4 o;
    o.x = f2bf(v.x); o.y = f2bf(v.y); o.z = f2bf(v.z); o.w = f2bf(v.w);
    reinterpret_cast<ushort4*>(d)[i] = o;
  }
}

// ------------- fused Q/K/V projection GEMMs (z selects which) -------------
// C[m,n] = sum_k A[m,k]*Bt[n,k]; z=0: ->Qh (bf16 [b,h,s,dk], *QK_SCALE)
// z=1: ->Kh (bf16 [b,h,s,dk]); z=2: ->Vt (bf16 [b,h,dk,s], transposed)
__global__ __launch_bounds__(256, 2) void gemm_qkv(const u16* __restrict__ qb,
                                                   const u16* __restrict__ kb,
                                                   const u16* __restrict__ vb,
                                                   const u16* __restrict__ wqb,
                                                   const u16* __restrict__ wkb,
                                                   const u16* __restrict__ wvb,
                                                   u16* __restrict__ Qh,
                                                   u16* __restrict__ Kh,
                                                   u16* __restrict__ Vt) {
  __shared__ __align__(16) u16 As[128 * 32];
  __shared__ __align__(16) u16 Bs[128 * 32];
  const int z = blockIdx.z;
  const u16* A = z == 0 ? qb : z == 1 ? kb : vb;
  const u16* Bt = z == 0 ? wqb : z == 1 ? wkb : wvb;
  const int tid = threadIdx.x;
  const int l = tid & 63, w = tid >> 6;
  const int m0 = blockIdx.x * 128, n0 = blockIdx.y * 128;
  const int wr = w >> 1, wc = w & 1;
  const int lq = l & 15, hi = l >> 4;

  f32x4 acc[4][4] = {};

  const int row_t = tid >> 2;        // + c*64
  const int col8 = (tid & 3) * 8;

  for (int k0 = 0; k0 < 1024; k0 += 32) {
#pragma unroll
    for (int c = 0; c < 2; ++c) {
      int row = c * 64 + row_t;
      const u16* ga = A + (size_t)(m0 + row) * 1024 + k0 + col8;
      const u16* gb = Bt + (size_t)(n0 + row) * 1024 + k0 + col8;
      __builtin_amdgcn_global_load_lds(
          (const __attribute__((address_space(1))) void*)ga,
          (__attribute__((address_space(3))) void*)&As[(c * 256 + w * 64) * 8], 16, 0, 0);
      __builtin_amdgcn_global_load_lds(
          (const __attribute__((address_space(1))) void*)gb,
          (__attribute__((address_space(3))) void*)&Bs[(c * 256 + w * 64) * 8], 16, 0, 0);
    }
    __syncthreads();
    short8 af[4], bf[4];
#pragma unroll
    for (int i = 0; i < 4; ++i) {
      af[i] = *(const short8*)&As[(wr * 64 + i * 16 + lq) * 32 + hi * 8];
      bf[i] = *(const short8*)&Bs[(wc * 64 + i * 16 + lq) * 32 + hi * 8];
    }
#pragma unroll
    for (int i = 0; i < 4; ++i)
#pragma unroll
      for (int j = 0; j < 4; ++j) acc[i][j] = mfma16(af[i], bf[j], acc[i][j]);
    __syncthreads();
  }

  const float oscale = z == 0 ? QK_SCALE : 1.0f;
#pragma unroll
  for (int i = 0; i < 4; ++i) {
#pragma unroll
    for (int j = 0; j < 4; ++j) {
      const int mg = m0 + wr * 64 + i * 16 + hi * 4;  // + r
      const int ng = n0 + wc * 64 + j * 16 + lq;
      const int h = ng >> 6, dk = ng & 63;
      if (z < 2) {
        u16* o = z == 0 ? Qh : Kh;
#pragma unroll
        for (int r = 0; r < 4; ++r) {
          int m = mg + r;
          int b = m >> 11, s = m & 2047;
          o[(((size_t)(b * NHEADS + h) * SS + s) << 6) + dk] = f2bf(acc[i][j][r] * oscale);
        }
      } else {
        const int b = mg >> 11, s = mg & 2047;  // s multiple of 4
        uint2 pk;
        pk.x = (u32)f2bf(acc[i][j][0]) | ((u32)f2bf(acc[i][j][1]) << 16);
        pk.y = (u32)f2bf(acc[i][j][2]) | ((u32)f2bf(acc[i][j][3]) << 16);
        *(uint2*)&Vt[(((size_t)(b * NHEADS + h) * DK + dk) << 11) + s] = pk;
      }
    }
  }
}

// ---------------- output GEMM: f32 out ----------------
__global__ __launch_bounds__(256, 2) void gemm_out(const u16* __restrict__ A,
                                                   const u16* __restrict__ Bt,
                                                   float* __restrict__ out) {
  __shared__ __align__(16) u16 As[128 * 32];
  __shared__ __align__(16) u16 Bs[128 * 32];
  const int tid = threadIdx.x;
  const int l = tid & 63, w = tid >> 6;
  const int m0 = blockIdx.x * 128, n0 = blockIdx.y * 128;
  const int wr = w >> 1, wc = w & 1;
  const int lq = l & 15, hi = l >> 4;

  f32x4 acc[4][4] = {};

  const int row_t = tid >> 2;
  const int col8 = (tid & 3) * 8;

  for (int k0 = 0; k0 < 1024; k0 += 32) {
#pragma unroll
    for (int c = 0; c < 2; ++c) {
      int row = c * 64 + row_t;
      const u16* ga = A + (size_t)(m0 + row) * 1024 + k0 + col8;
      const u16* gb = Bt + (size_t)(n0 + row) * 1024 + k0 + col8;
      __builtin_amdgcn_global_load_lds(
          (const __attribute__((address_space(1))) void*)ga,
          (__attribute__((address_space(3))) void*)&As[(c * 256 + w * 64) * 8], 16, 0, 0);
      __builtin_amdgcn_global_load_lds(
          (const __attribute__((address_space(1))) void*)gb,
          (__attribute__((address_space(3))) void*)&Bs[(c * 256 + w * 64) * 8], 16, 0, 0);
    }
    __syncthreads();
    short8 af[4], bf[4];
#pragma unroll
    for (int i = 0; i < 4; ++i) {
      af[i] = *(const short8*)&As[(wr * 64 + i * 16 + lq) * 32 + hi * 8];
      bf[i] = *(const short8*)&Bs[(wc * 64 + i * 16 + lq) * 32 + hi * 8];
    }
#pragma unroll
    for (int i = 0; i < 4; ++i)
#pragma unroll
      for (int j = 0; j < 4; ++j) acc[i][j] = mfma16(af[i], bf[j], acc[i][j]);
    __syncthreads();
  }

#pragma unroll
  for (int i = 0; i < 4; ++i)
#pragma unroll
    for (int j = 0; j < 4; ++j) {
      const int mg = m0 + wr * 64 + i * 16 + hi * 4;
      const int ng = n0 + wc * 64 + j * 16 + lq;
#pragma unroll
      for (int r = 0; r < 4; ++r) out[(size_t)(mg + r) * 1024 + ng] = acc[i][j][r];
    }
}

// ------- flash attention, 64 q/wave (4 groups): 2x arith intensity --------
// Qh: [b,h,s,dk] bf16 PRE-SCALED by 0.125*log2e ; Kh: [b,h,s,dk] bf16 ;
// Vt: [b,h,dk,s] bf16 ; out: [b*S+s, h*64+d] bf16
// Block = 256 threads (4 waves), 256 q rows (64 per wave, 4 groups of 16).
// Each K/V fragment ds_read feeds 4 MFMAs -> LDS traffic per FLOP halved
// vs R9; 4 independent per-group chains give intra-wave ILP.
__global__ __launch_bounds__(256, 2) void attn_kernel(const u16* __restrict__ Qh,
                                                      const u16* __restrict__ Kh,
                                                      const u16* __restrict__ Vt,
                                                      const int* __restrict__ mask,
                                                      u16* __restrict__ attn_out) {
  __shared__ __align__(16) u16 Ks[2][64 * 64];
  __shared__ __align__(16) u16 Vs[2][64 * 64];
  __shared__ __align__(16) float bias2[SS];
  const int tid = threadIdx.x;
  const int l = tid & 63, w = tid >> 6;  // w in 0..3
  // bijective XCD-chunk swizzle: 512 blocks, 8 XCDs, 64 per chunk
  int wg = ((int)blockIdx.x & 7) * 64 + ((int)blockIdx.x >> 3);
  const int qt = wg & 7, h = (wg >> 3) & 15, b = wg >> 7;
  const int lq = l & 15, hi = l >> 4;

  const int* mrow = mask + b * SS;
  for (int i = tid; i < SS; i += 256) bias2[i] = mrow[i] ? 0.0f : -1e13f;

  const size_t bh = (size_t)(b * NHEADS + h);
  const u16* Qp = Qh + bh * ((size_t)SS * DK);
  const u16* Kp = Kh + bh * ((size_t)SS * DK);
  const u16* Vp = Vt + bh * ((size_t)DK * SS);

  // staging: 256 threads x 2 insts x 16B per tensor cover a 64x64 bf16 tile.
  const int srow = tid >> 3;
  const int gchunk = (tid & 7) ^ (srow & 7);
  const u16* kg = Kp + (size_t)srow * 64 + gchunk * 8;          // + kv0*64
  const u16* vg = Vp + (size_t)srow * 2048 + gchunk * 8;        // + kv0
  const int ldsbase = w * 512;  // 8 rows * 64 elements per wave (inst0)

#define STAGE(buf, kv0)                                                         \
  do {                                                                          \
    __builtin_amdgcn_global_load_lds(                                           \
        (const __attribute__((address_space(1))) void*)(kg + (size_t)(kv0)*64), \
        (__attribute__((address_space(3))) void*)&Ks[buf][ldsbase], 16, 0, 0);  \
    __builtin_amdgcn_global_load_lds(                                           \
        (const __attribute__((address_space(1))) void*)(kg + (size_t)(kv0)*64 + \
                                                        32 * 64),               \
        (__attribute__((address_space(3))) void*)&Ks[buf][2048 + ldsbase], 16,  \
        0, 0);                                                                  \
    __builtin_amdgcn_global_load_lds(                                           \
        (const __attribute__((address_space(1))) void*)(vg + (kv0)),            \
        (__attribute__((address_space(3))) void*)&Vs[buf][ldsbase], 16, 0, 0);  \
    __builtin_amdgcn_global_load_lds(                                           \
        (const __attribute__((address_space(1))) void*)(vg + (kv0) + 32 * 2048),\
        (__attribute__((address_space(3))) void*)&Vs[buf][2048 + ldsbase], 16,  \
        0, 0);                                                                  \
  } while (0)

  const int q0 = qt * 256 + w * 64;
  short8 qf[4][2];
#pragma unroll
  for (int qg = 0; qg < 4; ++qg)
#pragma unroll
    for (int kd = 0; kd < 2; ++kd)
      qf[qg][kd] = *(const short8*)&Qp[(q0 + qg * 16 + lq) * 64 + kd * 32 + hi * 8];

  f32x4 oacc[4][4] = {};
  f32x4 psv[4] = {};
  const int rx = lq & 7;
  const int csw = ((hi ^ rx) * 8);  // swizzled chunk -> element offset

  STAGE(0, 0);
  __syncthreads();
  int cur = 0;

  for (int it = 0; it < 32; ++it) {
    const int kv0 = it * 64;
    if (it < 31) STAGE(cur ^ 1, kv0 + 64);

    // QK all 4 groups: K frags read once, reused 4x
    f32x4 st[4][4];
    __builtin_amdgcn_s_setprio(1);
#pragma unroll
    for (int t = 0; t < 4; ++t) {
      const u16* kp = &Ks[cur][(t * 16 + lq) * 64 + csw];
      short8 kf0 = *(const short8*)kp;
      short8 kf1 = *(const short8*)((uintptr_t)kp ^ 64);  // chunk ^4
      f32x4 bz = *(const f32x4*)&bias2[kv0 + t * 16 + hi * 4];
#pragma unroll
      for (int qg = 0; qg < 4; ++qg) {
        f32x4 zz = mfma16(kf0, qf[qg][0], bz);
        st[qg][t] = mfma16(kf1, qf[qg][1], zz);
      }
    }
    __builtin_amdgcn_s_setprio(0);

    // softmax + pack per group (exp2 fused into cvtpk inputs)
    short8 pfA[4], pfB[4];
#pragma unroll
    for (int qg = 0; qg < 4; ++qg) {
      u32 wd[4];
#pragma unroll
      for (int t2 = 0; t2 < 2; ++t2)
#pragma unroll
        for (int p = 0; p < 2; ++p) {
          float plo = __builtin_amdgcn_exp2f(st[qg][t2][2 * p]);
          float phi = __builtin_amdgcn_exp2f(st[qg][t2][2 * p + 1]);
          psv[qg][2 * p] += plo;
          psv[qg][2 * p + 1] += phi;
          wd[t2 * 2 + p] = cvtpk(plo, phi);
        }
      u32 xd[4];
#pragma unroll
      for (int t2 = 0; t2 < 2; ++t2)
#pragma unroll
        for (int p = 0; p < 2; ++p) {
          float plo = __builtin_amdgcn_exp2f(st[qg][2 + t2][2 * p]);
          float phi = __builtin_amdgcn_exp2f(st[qg][2 + t2][2 * p + 1]);
          psv[qg][2 * p] += plo;
          psv[qg][2 * p + 1] += phi;
          xd[t2 * 2 + p] = cvtpk(plo, phi);
        }
      pl32swap(wd[0], wd[2]);
      pl32swap(wd[1], wd[3]);
      pl16swap(wd[0], wd[2]);
      pl16swap(wd[1], wd[3]);
      uint4 pk = {wd[0], wd[1], wd[2], wd[3]};
      pfA[qg] = __builtin_bit_cast(short8, pk);
      pl32swap(xd[0], xd[2]);
      pl32swap(xd[1], xd[3]);
      pl16swap(xd[0], xd[2]);
      pl16swap(xd[1], xd[3]);
      uint4 pk2 = {xd[0], xd[1], xd[2], xd[3]};
      pfB[qg] = __builtin_bit_cast(short8, pk2);
    }

    // PV all 4 groups: V frags read once, reused 4x
    __builtin_amdgcn_s_setprio(1);
#pragma unroll
    for (int dt = 0; dt < 4; ++dt) {
      const u16* vp = &Vs[cur][(dt * 16 + lq) * 64 + csw];
      short8 vf0 = *(const short8*)vp;
      short8 vf1 = *(const short8*)((uintptr_t)vp ^ 64);
#pragma unroll
      for (int qg = 0; qg < 4; ++qg) {
        oacc[qg][dt] = mfma16(vf0, pfA[qg], oacc[qg][dt]);
        oacc[qg][dt] = mfma16(vf1, pfB[qg], oacc[qg][dt]);
      }
    }
    __builtin_amdgcn_s_setprio(0);
    __syncthreads();
    cur ^= 1;
  }

#pragma unroll
  for (int qg = 0; qg < 4; ++qg) {
    float lsum = psv[qg][0] + psv[qg][1] + psv[qg][2] + psv[qg][3];
    lsum += __shfl_xor(lsum, 16);
    lsum += __shfl_xor(lsum, 32);
    const float inv = 1.0f / lsum;
    const int q = q0 + qg * 16 + lq;
    const size_t obase = (((size_t)(b * SS + q)) << 10) + h * 64;
#pragma unroll
    for (int dt = 0; dt < 4; ++dt) {
      const int dbase = dt * 16 + hi * 4;
      uint2 pk;
      pk.x = (u32)f2bf(oacc[qg][dt][0] * inv) | ((u32)f2bf(oacc[qg][dt][1] * inv) << 16);
      pk.y = (u32)f2bf(oacc[qg][dt][2] * inv) | ((u32)f2bf(oacc[qg][dt][3] * inv) << 16);
      *(uint2*)&attn_out[obase + dbase] = pk;
    }
  }
#undef STAGE
}

extern "C" void kernel_launch(void* const* d_in, const int* in_sizes, int n_in,
                              void* d_out, int out_size, void* d_ws, size_t ws_size,
                              hipStream_t stream) {
  const float* q_in = (const float*)d_in[0];
  const float* k_in = (const float*)d_in[1];
  const float* v_in = (const float*)d_in[2];
  const int* mask = (const int*)d_in[3];
  const float* Wq = (const float*)d_in[4];
  const float* Wk = (const float*)d_in[5];
  const float* Wv = (const float*)d_in[6];
  const float* Wo = (const float*)d_in[7];

  char* ws = (char*)d_ws;
  const size_t MB = 1ull << 20;
  u16* qb  = (u16*)(ws + 0 * MB);
  u16* kb  = (u16*)(ws + 16 * MB);
  u16* vb  = (u16*)(ws + 32 * MB);
  u16* wqb = (u16*)(ws + 48 * MB);
  u16* wkb = (u16*)(ws + 50 * MB);
  u16* wvb = (u16*)(ws + 52 * MB);
  u16* wob = (u16*)(ws + 54 * MB);
  u16* Qh  = (u16*)(ws + 56 * MB);
  u16* Kh  = (u16*)(ws + 72 * MB);
  u16* Vt  = (u16*)(ws + 88 * MB);
  u16* attn = (u16*)(ws + 104 * MB);  // total 120MB

  const int NX4 = (M_TOT * D_MODEL) / 4;
  const int NW4 = (D_MODEL * D_MODEL) / 4;
  cvt3_kernel<<<dim3(2048, 3), 256, 0, stream>>>(q_in, k_in, v_in, qb, kb, vb, NX4);
  cvt4_kernel<<<dim3(512, 4), 256, 0, stream>>>(Wq, Wk, Wv, Wo, wqb, wkb, wvb, wob, NW4);

  gemm_qkv<<<dim3(M_TOT / 128, D_MODEL / 128, 3), 256, 0, stream>>>(
      qb, kb, vb, wqb, wkb, wvb, Qh, Kh, Vt);

  attn_kernel<<<512, 256, 0, stream>>>(Qh, Kh, Vt, mask, attn);

  gemm_out<<<dim3(M_TOT / 128, D_MODEL / 128), 256, 0, stream>>>(attn, wob, (float*)d_out);
}

// Round 11
// 207.989 us; speedup vs baseline: 1.1484x; 1.0061x over previous
//
#include <hip/hip_runtime.h>
#include <hip/hip_bf16.h>
#include <stdint.h>

typedef unsigned short u16;
typedef unsigned int u32;

#define D_MODEL 1024
#define NHEADS 16
#define DK 64
#define BB 4
#define SS 2048
#define M_TOT (BB * SS)  // 8192
#define QK_SCALE 0.18033688011112042f  // 0.125 * log2(e)

typedef __attribute__((ext_vector_type(8))) short short8;
typedef __attribute__((ext_vector_type(8))) __bf16 bf16x8;
typedef __attribute__((ext_vector_type(4))) float f32x4;

static __device__ __forceinline__ f32x4 mfma16(short8 a, short8 b, f32x4 c) {
  return __builtin_amdgcn_mfma_f32_16x16x32_bf16(
      __builtin_bit_cast(bf16x8, a), __builtin_bit_cast(bf16x8, b), c, 0, 0, 0);
}

// round-to-nearest-even f32 -> bf16
static __device__ __forceinline__ u16 f2bf(float f) {
  u32 u = __builtin_bit_cast(u32, f);
  u += 0x7fffu + ((u >> 16) & 1u);
  return (u16)(u >> 16);
}

// packed f32x2 -> bf16x2 (RNE); dst.lo = lo, dst.hi = hi
static __device__ __forceinline__ u32 cvtpk(float lo, float hi) {
  u32 r;
  asm("v_cvt_pk_bf16_f32 %0, %1, %2" : "=v"(r) : "v"(lo), "v"(hi));
  return r;
}
// swap a.lanes[32:63] <-> b.lanes[0:31]   (vdst.hi32 <-> vsrc.lo32)
static __device__ __forceinline__ void pl32swap(u32& a, u32& b) {
  asm("v_permlane32_swap_b32 %0, %1" : "+v"(a), "+v"(b));
}
// swap a.odd-16-rows <-> b.even-16-rows
static __device__ __forceinline__ void pl16swap(u32& a, u32& b) {
  asm("v_permlane16_swap_b32 %0, %1" : "+v"(a), "+v"(b));
}

// ---------------- f32 -> bf16 convert, all 7 tensors, one launch ----------
__global__ void cvt7_kernel(const float* __restrict__ s0, const float* __restrict__ s1,
                            const float* __restrict__ s2, const float* __restrict__ s3,
                            const float* __restrict__ s4, const float* __restrict__ s5,
                            const float* __restrict__ s6, u16* __restrict__ d0,
                            u16* __restrict__ d1, u16* __restrict__ d2,
                            u16* __restrict__ d3, u16* __restrict__ d4,
                            u16* __restrict__ d5, u16* __restrict__ d6,
                            int n4big, int n4small) {
  const int y = blockIdx.y;
  const float* s = y == 0 ? s0 : y == 1 ? s1 : y == 2 ? s2 : y == 3 ? s3
                   : y == 4 ? s4 : y == 5 ? s5 : s6;
  u16* d = y == 0 ? d0 : y == 1 ? d1 : y == 2 ? d2 : y == 3 ? d3
           : y == 4 ? d4 : y == 5 ? d5 : d6;
  const int n4 = y < 3 ? n4big : n4small;
  int stride = gridDim.x * blockDim.x;
  for (int i = blockIdx.x * blockDim.x + threadIdx.x; i < n4; i += stride) {
    float4 v = reinterpret_cast<const float4*>(s)[i];
    ushort4 o;
    o.x = f2bf(v.x); o.y = f2bf(v.y); o.z = f2bf(v.z); o.w = f2bf(v.w);
    reinterpret_cast<ushort4*>(d)[i] = o;
  }
}

// XCD-co-designed tile map: 512 tiles (64 m x 8 n), 8 XCDs.
// hw block L -> xcd = L&7 (dispatch round-robin), idx = L>>3.
// Each XCD owns m-panels [xcd*8, xcd*8+8) over all 8 n: its 8 A-panels (2MB)
// + all W-panels (2MB) stay L2-resident.
static __device__ __forceinline__ void tile_map(int L, int& m0, int& n0) {
  const int xcd = L & 7, idx = L >> 3;
  m0 = (xcd * 8 + (idx >> 3)) * 128;
  n0 = (idx & 7) * 128;
}

// ------------- fused Q/K/V projection GEMMs (z selects which) -------------
// C[m,n] = sum_k A[m,k]*Bt[n,k]; z=0: ->Qh (bf16 [b,h,s,dk], *QK_SCALE)
// z=1: ->Kh (bf16 [b,h,s,dk]); z=2: ->Vt (bf16 [b,h,dk,s], transposed)
__global__ __launch_bounds__(256, 2) void gemm_qkv(const u16* __restrict__ qb,
                                                   const u16* __restrict__ kb,
                                                   const u16* __restrict__ vb,
                                                   const u16* __restrict__ wqb,
                                                   const u16* __restrict__ wkb,
                                                   const u16* __restrict__ wvb,
                                                   u16* __restrict__ Qh,
                                                   u16* __restrict__ Kh,
                                                   u16* __restrict__ Vt) {
  __shared__ __align__(16) u16 As[128 * 32];
  __shared__ __align__(16) u16 Bs[128 * 32];
  const int z = blockIdx.z;
  const u16* A = z == 0 ? qb : z == 1 ? kb : vb;
  const u16* Bt = z == 0 ? wqb : z == 1 ? wkb : wvb;
  const int tid = threadIdx.x;
  const int l = tid & 63, w = tid >> 6;
  int m0, n0;
  tile_map((int)blockIdx.x, m0, n0);
  const int wr = w >> 1, wc = w & 1;
  const int lq = l & 15, hi = l >> 4;

  f32x4 acc[4][4] = {};

  const int row_t = tid >> 2;        // + c*64
  const int col8 = (tid & 3) * 8;

  for (int k0 = 0; k0 < 1024; k0 += 32) {
#pragma unroll
    for (int c = 0; c < 2; ++c) {
      int row = c * 64 + row_t;
      const u16* ga = A + (size_t)(m0 + row) * 1024 + k0 + col8;
      const u16* gb = Bt + (size_t)(n0 + row) * 1024 + k0 + col8;
      __builtin_amdgcn_global_load_lds(
          (const __attribute__((address_space(1))) void*)ga,
          (__attribute__((address_space(3))) void*)&As[(c * 256 + w * 64) * 8], 16, 0, 0);
      __builtin_amdgcn_global_load_lds(
          (const __attribute__((address_space(1))) void*)gb,
          (__attribute__((address_space(3))) void*)&Bs[(c * 256 + w * 64) * 8], 16, 0, 0);
    }
    __syncthreads();
    short8 af[4], bf[4];
#pragma unroll
    for (int i = 0; i < 4; ++i) {
      af[i] = *(const short8*)&As[(wr * 64 + i * 16 + lq) * 32 + hi * 8];
      bf[i] = *(const short8*)&Bs[(wc * 64 + i * 16 + lq) * 32 + hi * 8];
    }
#pragma unroll
    for (int i = 0; i < 4; ++i)
#pragma unroll
      for (int j = 0; j < 4; ++j) acc[i][j] = mfma16(af[i], bf[j], acc[i][j]);
    __syncthreads();
  }

  const float oscale = z == 0 ? QK_SCALE : 1.0f;
#pragma unroll
  for (int i = 0; i < 4; ++i) {
#pragma unroll
    for (int j = 0; j < 4; ++j) {
      const int mg = m0 + wr * 64 + i * 16 + hi * 4;  // + r
      const int ng = n0 + wc * 64 + j * 16 + lq;
      const int h = ng >> 6, dk = ng & 63;
      if (z < 2) {
        u16* o = z == 0 ? Qh : Kh;
#pragma unroll
        for (int r = 0; r < 4; ++r) {
          int m = mg + r;
          int b = m >> 11, s = m & 2047;
          o[(((size_t)(b * NHEADS + h) * SS + s) << 6) + dk] = f2bf(acc[i][j][r] * oscale);
        }
      } else {
        const int b = mg >> 11, s = mg & 2047;  // s multiple of 4
        uint2 pk;
        pk.x = (u32)f2bf(acc[i][j][0]) | ((u32)f2bf(acc[i][j][1]) << 16);
        pk.y = (u32)f2bf(acc[i][j][2]) | ((u32)f2bf(acc[i][j][3]) << 16);
        *(uint2*)&Vt[(((size_t)(b * NHEADS + h) * DK + dk) << 11) + s] = pk;
      }
    }
  }
}

// ---------------- output GEMM: f32 out ----------------
__global__ __launch_bounds__(256, 2) void gemm_out(const u16* __restrict__ A,
                                                   const u16* __restrict__ Bt,
                                                   float* __restrict__ out) {
  __shared__ __align__(16) u16 As[128 * 32];
  __shared__ __align__(16) u16 Bs[128 * 32];
  const int tid = threadIdx.x;
  const int l = tid & 63, w = tid >> 6;
  int m0, n0;
  tile_map((int)blockIdx.x, m0, n0);
  const int wr = w >> 1, wc = w & 1;
  const int lq = l & 15, hi = l >> 4;

  f32x4 acc[4][4] = {};

  const int row_t = tid >> 2;
  const int col8 = (tid & 3) * 8;

  for (int k0 = 0; k0 < 1024; k0 += 32) {
#pragma unroll
    for (int c = 0; c < 2; ++c) {
      int row = c * 64 + row_t;
      const u16* ga = A + (size_t)(m0 + row) * 1024 + k0 + col8;
      const u16* gb = Bt + (size_t)(n0 + row) * 1024 + k0 + col8;
      __builtin_amdgcn_global_load_lds(
          (const __attribute__((address_space(1))) void*)ga,
          (__attribute__((address_space(3))) void*)&As[(c * 256 + w * 64) * 8], 16, 0, 0);
      __builtin_amdgcn_global_load_lds(
          (const __attribute__((address_space(1))) void*)gb,
          (__attribute__((address_space(3))) void*)&Bs[(c * 256 + w * 64) * 8], 16, 0, 0);
    }
    __syncthreads();
    short8 af[4], bf[4];
#pragma unroll
    for (int i = 0; i < 4; ++i) {
      af[i] = *(const short8*)&As[(wr * 64 + i * 16 + lq) * 32 + hi * 8];
      bf[i] = *(const short8*)&Bs[(wc * 64 + i * 16 + lq) * 32 + hi * 8];
    }
#pragma unroll
    for (int i = 0; i < 4; ++i)
#pragma unroll
      for (int j = 0; j < 4; ++j) acc[i][j] = mfma16(af[i], bf[j], acc[i][j]);
    __syncthreads();
  }

#pragma unroll
  for (int i = 0; i < 4; ++i)
#pragma unroll
    for (int j = 0; j < 4; ++j) {
      const int mg = m0 + wr * 64 + i * 16 + hi * 4;
      const int ng = n0 + wc * 64 + j * 16 + lq;
#pragma unroll
      for (int r = 0; r < 4; ++r) out[(size_t)(mg + r) * 1024 + ng] = acc[i][j][r];
    }
}

// ------- flash attention, 64 q/wave (4 groups) — unchanged from R10 -------
__global__ __launch_bounds__(256, 2) void attn_kernel(const u16* __restrict__ Qh,
                                                      const u16* __restrict__ Kh,
                                                      const u16* __restrict__ Vt,
                                                      const int* __restrict__ mask,
                                                      u16* __restrict__ attn_out) {
  __shared__ __align__(16) u16 Ks[2][64 * 64];
  __shared__ __align__(16) u16 Vs[2][64 * 64];
  __shared__ __align__(16) float bias2[SS];
  const int tid = threadIdx.x;
  const int l = tid & 63, w = tid >> 6;  // w in 0..3
  // bijective XCD-chunk swizzle: 512 blocks, 8 XCDs, 64 per chunk
  int wg = ((int)blockIdx.x & 7) * 64 + ((int)blockIdx.x >> 3);
  const int qt = wg & 7, h = (wg >> 3) & 15, b = wg >> 7;
  const int lq = l & 15, hi = l >> 4;

  const int* mrow = mask + b * SS;
  for (int i = tid; i < SS; i += 256) bias2[i] = mrow[i] ? 0.0f : -1e13f;

  const size_t bh = (size_t)(b * NHEADS + h);
  const u16* Qp = Qh + bh * ((size_t)SS * DK);
  const u16* Kp = Kh + bh * ((size_t)SS * DK);
  const u16* Vp = Vt + bh * ((size_t)DK * SS);

  const int srow = tid >> 3;
  const int gchunk = (tid & 7) ^ (srow & 7);
  const u16* kg = Kp + (size_t)srow * 64 + gchunk * 8;          // + kv0*64
  const u16* vg = Vp + (size_t)srow * 2048 + gchunk * 8;        // + kv0
  const int ldsbase = w * 512;  // 8 rows * 64 elements per wave (inst0)

#define STAGE(buf, kv0)                                                         \
  do {                                                                          \
    __builtin_amdgcn_global_load_lds(                                           \
        (const __attribute__((address_space(1))) void*)(kg + (size_t)(kv0)*64), \
        (__attribute__((address_space(3))) void*)&Ks[buf][ldsbase], 16, 0, 0);  \
    __builtin_amdgcn_global_load_lds(                                           \
        (const __attribute__((address_space(1))) void*)(kg + (size_t)(kv0)*64 + \
                                                        32 * 64),               \
        (__attribute__((address_space(3))) void*)&Ks[buf][2048 + ldsbase], 16,  \
        0, 0);                                                                  \
    __builtin_amdgcn_global_load_lds(                                           \
        (const __attribute__((address_space(1))) void*)(vg + (kv0)),            \
        (__attribute__((address_space(3))) void*)&Vs[buf][ldsbase], 16, 0, 0);  \
    __builtin_amdgcn_global_load_lds(                                           \
        (const __attribute__((address_space(1))) void*)(vg + (kv0) + 32 * 2048),\
        (__attribute__((address_space(3))) void*)&Vs[buf][2048 + ldsbase], 16,  \
        0, 0);                                                                  \
  } while (0)

  const int q0 = qt * 256 + w * 64;
  short8 qf[4][2];
#pragma unroll
  for (int qg = 0; qg < 4; ++qg)
#pragma unroll
    for (int kd = 0; kd < 2; ++kd)
      qf[qg][kd] = *(const short8*)&Qp[(q0 + qg * 16 + lq) * 64 + kd * 32 + hi * 8];

  f32x4 oacc[4][4] = {};
  f32x4 psv[4] = {};
  const int rx = lq & 7;
  const int csw = ((hi ^ rx) * 8);  // swizzled chunk -> element offset

  STAGE(0, 0);
  __syncthreads();
  int cur = 0;

  for (int it = 0; it < 32; ++it) {
    const int kv0 = it * 64;
    if (it < 31) STAGE(cur ^ 1, kv0 + 64);

    // QK all 4 groups: K frags read once, reused 4x
    f32x4 st[4][4];
    __builtin_amdgcn_s_setprio(1);
#pragma unroll
    for (int t = 0; t < 4; ++t) {
      const u16* kp = &Ks[cur][(t * 16 + lq) * 64 + csw];
      short8 kf0 = *(const short8*)kp;
      short8 kf1 = *(const short8*)((uintptr_t)kp ^ 64);  // chunk ^4
      f32x4 bz = *(const f32x4*)&bias2[kv0 + t * 16 + hi * 4];
#pragma unroll
      for (int qg = 0; qg < 4; ++qg) {
        f32x4 zz = mfma16(kf0, qf[qg][0], bz);
        st[qg][t] = mfma16(kf1, qf[qg][1], zz);
      }
    }
    __builtin_amdgcn_s_setprio(0);

    // softmax + pack per group (exp2 fused into cvtpk inputs)
    short8 pfA[4], pfB[4];
#pragma unroll
    for (int qg = 0; qg < 4; ++qg) {
      u32 wd[4];
#pragma unroll
      for (int t2 = 0; t2 < 2; ++t2)
#pragma unroll
        for (int p = 0; p < 2; ++p) {
          float plo = __builtin_amdgcn_exp2f(st[qg][t2][2 * p]);
          float phi = __builtin_amdgcn_exp2f(st[qg][t2][2 * p + 1]);
          psv[qg][2 * p] += plo;
          psv[qg][2 * p + 1] += phi;
          wd[t2 * 2 + p] = cvtpk(plo, phi);
        }
      u32 xd[4];
#pragma unroll
      for (int t2 = 0; t2 < 2; ++t2)
#pragma unroll
        for (int p = 0; p < 2; ++p) {
          float plo = __builtin_amdgcn_exp2f(st[qg][2 + t2][2 * p]);
          float phi = __builtin_amdgcn_exp2f(st[qg][2 + t2][2 * p + 1]);
          psv[qg][2 * p] += plo;
          psv[qg][2 * p + 1] += phi;
          xd[t2 * 2 + p] = cvtpk(plo, phi);
        }
      pl32swap(wd[0], wd[2]);
      pl32swap(wd[1], wd[3]);
      pl16swap(wd[0], wd[2]);
      pl16swap(wd[1], wd[3]);
      uint4 pk = {wd[0], wd[1], wd[2], wd[3]};
      pfA[qg] = __builtin_bit_cast(short8, pk);
      pl32swap(xd[0], xd[2]);
      pl32swap(xd[1], xd[3]);
      pl16swap(xd[0], xd[2]);
      pl16swap(xd[1], xd[3]);
      uint4 pk2 = {xd[0], xd[1], xd[2], xd[3]};
      pfB[qg] = __builtin_bit_cast(short8, pk2);
    }

    // PV all 4 groups: V frags read once, reused 4x
    __builtin_amdgcn_s_setprio(1);
#pragma unroll
    for (int dt = 0; dt < 4; ++dt) {
      const u16* vp = &Vs[cur][(dt * 16 + lq) * 64 + csw];
      short8 vf0 = *(const short8*)vp;
      short8 vf1 = *(const short8*)((uintptr_t)vp ^ 64);
#pragma unroll
      for (int qg = 0; qg < 4; ++qg) {
        oacc[qg][dt] = mfma16(vf0, pfA[qg], oacc[qg][dt]);
        oacc[qg][dt] = mfma16(vf1, pfB[qg], oacc[qg][dt]);
      }
    }
    __builtin_amdgcn_s_setprio(0);
    __syncthreads();
    cur ^= 1;
  }

#pragma unroll
  for (int qg = 0; qg < 4; ++qg) {
    float lsum = psv[qg][0] + psv[qg][1] + psv[qg][2] + psv[qg][3];
    lsum += __shfl_xor(lsum, 16);
    lsum += __shfl_xor(lsum, 32);
    const float inv = 1.0f / lsum;
    const int q = q0 + qg * 16 + lq;
    const size_t obase = (((size_t)(b * SS + q)) << 10) + h * 64;
#pragma unroll
    for (int dt = 0; dt < 4; ++dt) {
      const int dbase = dt * 16 + hi * 4;
      uint2 pk;
      pk.x = (u32)f2bf(oacc[qg][dt][0] * inv) | ((u32)f2bf(oacc[qg][dt][1] * inv) << 16);
      pk.y = (u32)f2bf(oacc[qg][dt][2] * inv) | ((u32)f2bf(oacc[qg][dt][3] * inv) << 16);
      *(uint2*)&attn_out[obase + dbase] = pk;
    }
  }
#undef STAGE
}

extern "C" void kernel_launch(void* const* d_in, const int* in_sizes, int n_in,
                              void* d_out, int out_size, void* d_ws, size_t ws_size,
                              hipStream_t stream) {
  const float* q_in = (const float*)d_in[0];
  const float* k_in = (const float*)d_in[1];
  const float* v_in = (const float*)d_in[2];
  const int* mask = (const int*)d_in[3];
  const float* Wq = (const float*)d_in[4];
  const float* Wk = (const float*)d_in[5];
  const float* Wv = (const float*)d_in[6];
  const float* Wo = (const float*)d_in[7];

  char* ws = (char*)d_ws;
  const size_t MB = 1ull << 20;
  u16* qb  = (u16*)(ws + 0 * MB);
  u16* kb  = (u16*)(ws + 16 * MB);
  u16* vb  = (u16*)(ws + 32 * MB);
  u16* wqb = (u16*)(ws + 48 * MB);
  u16* wkb = (u16*)(ws + 50 * MB);
  u16* wvb = (u16*)(ws + 52 * MB);
  u16* wob = (u16*)(ws + 54 * MB);
  u16* Qh  = (u16*)(ws + 56 * MB);
  u16* Kh  = (u16*)(ws + 72 * MB);
  u16* Vt  = (u16*)(ws + 88 * MB);
  u16* attn = (u16*)(ws + 104 * MB);  // total 120MB

  const int NX4 = (M_TOT * D_MODEL) / 4;
  const int NW4 = (D_MODEL * D_MODEL) / 4;
  cvt7_kernel<<<dim3(2048, 7), 256, 0, stream>>>(
      q_in, k_in, v_in, Wq, Wk, Wv, Wo,
      qb, kb, vb, wqb, wkb, wvb, wob, NX4, NW4);

  gemm_qkv<<<dim3(512, 1, 3), 256, 0, stream>>>(
      qb, kb, vb, wqb, wkb, wvb, Qh, Kh, Vt);

  attn_kernel<<<512, 256, 0, stream>>>(Qh, Kh, Vt, mask, attn);

  gemm_out<<<512, 256, 0, stream>>>(attn, wob, (float*)d_out);
}

// Round 12
// 207.160 us; speedup vs baseline: 1.1530x; 1.0040x over previous
//
#include <hip/hip_runtime.h>
#include <hip/hip_bf16.h>
#include <stdint.h>

typedef unsigned short u16;
typedef unsigned int u32;

#define D_MODEL 1024
#define NHEADS 16
#define DK 64
#define BB 4
#define SS 2048
#define M_TOT (BB * SS)  // 8192
#define QK_SCALE 0.18033688011112042f  // 0.125 * log2(e)

typedef __attribute__((ext_vector_type(8))) short short8;
typedef __attribute__((ext_vector_type(8))) __bf16 bf16x8;
typedef __attribute__((ext_vector_type(4))) float f32x4;

static __device__ __forceinline__ f32x4 mfma16(short8 a, short8 b, f32x4 c) {
  return __builtin_amdgcn_mfma_f32_16x16x32_bf16(
      __builtin_bit_cast(bf16x8, a), __builtin_bit_cast(bf16x8, b), c, 0, 0, 0);
}

// round-to-nearest-even f32 -> bf16
static __device__ __forceinline__ u16 f2bf(float f) {
  u32 u = __builtin_bit_cast(u32, f);
  u += 0x7fffu + ((u >> 16) & 1u);
  return (u16)(u >> 16);
}

// packed f32x2 -> bf16x2 (RNE); dst.lo = lo, dst.hi = hi
static __device__ __forceinline__ u32 cvtpk(float lo, float hi) {
  u32 r;
  asm("v_cvt_pk_bf16_f32 %0, %1, %2" : "=v"(r) : "v"(lo), "v"(hi));
  return r;
}
// swap a.lanes[32:63] <-> b.lanes[0:31]   (vdst.hi32 <-> vsrc.lo32)
static __device__ __forceinline__ void pl32swap(u32& a, u32& b) {
  asm("v_permlane32_swap_b32 %0, %1" : "+v"(a), "+v"(b));
}
// swap a.odd-16-rows <-> b.even-16-rows
static __device__ __forceinline__ void pl16swap(u32& a, u32& b) {
  asm("v_permlane16_swap_b32 %0, %1" : "+v"(a), "+v"(b));
}

// counted waits: loads stay in flight across barriers (T4)
#define WAITV4 asm volatile("s_waitcnt vmcnt(4)" ::: "memory")
#define WAITV0 asm volatile("s_waitcnt vmcnt(0)" ::: "memory")

// ---------------- f32 -> bf16 convert, all 7 tensors, one launch ----------
__global__ void cvt7_kernel(const float* __restrict__ s0, const float* __restrict__ s1,
                            const float* __restrict__ s2, const float* __restrict__ s3,
                            const float* __restrict__ s4, const float* __restrict__ s5,
                            const float* __restrict__ s6, u16* __restrict__ d0,
                            u16* __restrict__ d1, u16* __restrict__ d2,
                            u16* __restrict__ d3, u16* __restrict__ d4,
                            u16* __restrict__ d5, u16* __restrict__ d6,
                            int n4big, int n4small) {
  const int y = blockIdx.y;
  const float* s = y == 0 ? s0 : y == 1 ? s1 : y == 2 ? s2 : y == 3 ? s3
                   : y == 4 ? s4 : y == 5 ? s5 : s6;
  u16* d = y == 0 ? d0 : y == 1 ? d1 : y == 2 ? d2 : y == 3 ? d3
           : y == 4 ? d4 : y == 5 ? d5 : d6;
  const int n4 = y < 3 ? n4big : n4small;
  int stride = gridDim.x * blockDim.x;
  for (int i = blockIdx.x * blockDim.x + threadIdx.x; i < n4; i += stride) {
    float4 v = reinterpret_cast<const float4*>(s)[i];
    ushort4 o;
    o.x = f2bf(v.x); o.y = f2bf(v.y); o.z = f2bf(v.z); o.w = f2bf(v.w);
    reinterpret_cast<ushort4*>(d)[i] = o;
  }
}

// XCD-co-designed tile map: 512 tiles (64 m x 8 n), 8 XCDs.
static __device__ __forceinline__ void tile_map(int L, int& m0, int& n0) {
  const int xcd = L & 7, idx = L >> 3;
  m0 = (xcd * 8 + (idx >> 3)) * 128;
  n0 = (idx & 7) * 128;
}

// ------------- fused Q/K/V projection GEMMs (z selects which) -------------
// 3-buffer LDS, 2-ahead prefetch, counted vmcnt(4), one s_barrier per k-step.
__global__ __launch_bounds__(256, 3) void gemm_qkv(const u16* __restrict__ qb,
                                                   const u16* __restrict__ kb,
                                                   const u16* __restrict__ vb,
                                                   const u16* __restrict__ wqb,
                                                   const u16* __restrict__ wkb,
                                                   const u16* __restrict__ wvb,
                                                   u16* __restrict__ Qh,
                                                   u16* __restrict__ Kh,
                                                   u16* __restrict__ Vt) {
  __shared__ __align__(16) u16 As[3][128 * 32];
  __shared__ __align__(16) u16 Bs[3][128 * 32];
  const int z = blockIdx.z;
  const u16* A = z == 0 ? qb : z == 1 ? kb : vb;
  const u16* Bt = z == 0 ? wqb : z == 1 ? wkb : wvb;
  const int tid = threadIdx.x;
  const int l = tid & 63, w = tid >> 6;
  int m0, n0;
  tile_map((int)blockIdx.x, m0, n0);
  const int wr = w >> 1, wc = w & 1;
  const int lq = l & 15, hi = l >> 4;

  f32x4 acc[4][4] = {};

  const int row_t = tid >> 2;        // + c*64
  const int col8 = (tid & 3) * 8;

#define GSTAGE(buf, kt)                                                        \
  do {                                                                         \
    _Pragma("unroll")                                                          \
    for (int c = 0; c < 2; ++c) {                                              \
      int row = c * 64 + row_t;                                                \
      const u16* ga = A + (size_t)(m0 + row) * 1024 + (kt) * 32 + col8;        \
      const u16* gb = Bt + (size_t)(n0 + row) * 1024 + (kt) * 32 + col8;       \
      __builtin_amdgcn_global_load_lds(                                        \
          (const __attribute__((address_space(1))) void*)ga,                   \
          (__attribute__((address_space(3))) void*)&As[buf][(c * 256 + w * 64) * 8], \
          16, 0, 0);                                                           \
      __builtin_amdgcn_global_load_lds(                                        \
          (const __attribute__((address_space(1))) void*)gb,                   \
          (__attribute__((address_space(3))) void*)&Bs[buf][(c * 256 + w * 64) * 8], \
          16, 0, 0);                                                           \
    }                                                                          \
  } while (0)

  auto compute = [&](int kbuf) {
    short8 af[4], bf[4];
#pragma unroll
    for (int i = 0; i < 4; ++i) {
      af[i] = *(const short8*)&As[kbuf][(wr * 64 + i * 16 + lq) * 32 + hi * 8];
      bf[i] = *(const short8*)&Bs[kbuf][(wc * 64 + i * 16 + lq) * 32 + hi * 8];
    }
#pragma unroll
    for (int i = 0; i < 4; ++i)
#pragma unroll
      for (int j = 0; j < 4; ++j) acc[i][j] = mfma16(af[i], bf[j], acc[i][j]);
  };

  GSTAGE(0, 0);
  GSTAGE(1, 1);
  for (int kt = 0; kt < 31; ++kt) {
    WAITV4;                             // S(kt) landed (S(kt+1) may fly)
    __builtin_amdgcn_s_barrier();       // all waves done reading buf[(kt-1)%3]
    if (kt < 30) GSTAGE((kt + 2) % 3, kt + 2);
    compute(kt % 3);
  }
  WAITV0;
  __builtin_amdgcn_s_barrier();
  compute(31 % 3);

  const float oscale = z == 0 ? QK_SCALE : 1.0f;
#pragma unroll
  for (int i = 0; i < 4; ++i) {
#pragma unroll
    for (int j = 0; j < 4; ++j) {
      const int mg = m0 + wr * 64 + i * 16 + hi * 4;  // + r
      const int ng = n0 + wc * 64 + j * 16 + lq;
      const int h = ng >> 6, dk = ng & 63;
      if (z < 2) {
        u16* o = z == 0 ? Qh : Kh;
#pragma unroll
        for (int r = 0; r < 4; ++r) {
          int m = mg + r;
          int b = m >> 11, s = m & 2047;
          o[(((size_t)(b * NHEADS + h) * SS + s) << 6) + dk] = f2bf(acc[i][j][r] * oscale);
        }
      } else {
        const int b = mg >> 11, s = mg & 2047;  // s multiple of 4
        uint2 pk;
        pk.x = (u32)f2bf(acc[i][j][0]) | ((u32)f2bf(acc[i][j][1]) << 16);
        pk.y = (u32)f2bf(acc[i][j][2]) | ((u32)f2bf(acc[i][j][3]) << 16);
        *(uint2*)&Vt[(((size_t)(b * NHEADS + h) * DK + dk) << 11) + s] = pk;
      }
    }
  }
#undef GSTAGE
}

// ---------------- output GEMM: f32 out, same pipeline ----------------
__global__ __launch_bounds__(256, 3) void gemm_out(const u16* __restrict__ A,
                                                   const u16* __restrict__ Bt,
                                                   float* __restrict__ out) {
  __shared__ __align__(16) u16 As[3][128 * 32];
  __shared__ __align__(16) u16 Bs[3][128 * 32];
  const int tid = threadIdx.x;
  const int l = tid & 63, w = tid >> 6;
  int m0, n0;
  tile_map((int)blockIdx.x, m0, n0);
  const int wr = w >> 1, wc = w & 1;
  const int lq = l & 15, hi = l >> 4;

  f32x4 acc[4][4] = {};

  const int row_t = tid >> 2;
  const int col8 = (tid & 3) * 8;

#define GSTAGE(buf, kt)                                                        \
  do {                                                                         \
    _Pragma("unroll")                                                          \
    for (int c = 0; c < 2; ++c) {                                              \
      int row = c * 64 + row_t;                                                \
      const u16* ga = A + (size_t)(m0 + row) * 1024 + (kt) * 32 + col8;        \
      const u16* gb = Bt + (size_t)(n0 + row) * 1024 + (kt) * 32 + col8;       \
      __builtin_amdgcn_global_load_lds(                                        \
          (const __attribute__((address_space(1))) void*)ga,                   \
          (__attribute__((address_space(3))) void*)&As[buf][(c * 256 + w * 64) * 8], \
          16, 0, 0);                                                           \
      __builtin_amdgcn_global_load_lds(                                        \
          (const __attribute__((address_space(1))) void*)gb,                   \
          (__attribute__((address_space(3))) void*)&Bs[buf][(c * 256 + w * 64) * 8], \
          16, 0, 0);                                                           \
    }                                                                          \
  } while (0)

  auto compute = [&](int kbuf) {
    short8 af[4], bf[4];
#pragma unroll
    for (int i = 0; i < 4; ++i) {
      af[i] = *(const short8*)&As[kbuf][(wr * 64 + i * 16 + lq) * 32 + hi * 8];
      bf[i] = *(const short8*)&Bs[kbuf][(wc * 64 + i * 16 + lq) * 32 + hi * 8];
    }
#pragma unroll
    for (int i = 0; i < 4; ++i)
#pragma unroll
      for (int j = 0; j < 4; ++j) acc[i][j] = mfma16(af[i], bf[j], acc[i][j]);
  };

  GSTAGE(0, 0);
  GSTAGE(1, 1);
  for (int kt = 0; kt < 31; ++kt) {
    WAITV4;
    __builtin_amdgcn_s_barrier();
    if (kt < 30) GSTAGE((kt + 2) % 3, kt + 2);
    compute(kt % 3);
  }
  WAITV0;
  __builtin_amdgcn_s_barrier();
  compute(31 % 3);

#pragma unroll
  for (int i = 0; i < 4; ++i)
#pragma unroll
    for (int j = 0; j < 4; ++j) {
      const int mg = m0 + wr * 64 + i * 16 + hi * 4;
      const int ng = n0 + wc * 64 + j * 16 + lq;
#pragma unroll
      for (int r = 0; r < 4; ++r) out[(size_t)(mg + r) * 1024 + ng] = acc[i][j][r];
    }
#undef GSTAGE
}

// ------- flash attention, 64 q/wave, 3-buffer counted-vmcnt pipeline ------
// Qh: [b,h,s,dk] bf16 PRE-SCALED by 0.125*log2e ; Kh: [b,h,s,dk] bf16 ;
// Vt: [b,h,dk,s] bf16 ; out: [b*S+s, h*64+d] bf16
// Block = 256 threads (4 waves), 256 q rows (64 per wave, 4 groups of 16).
__global__ __launch_bounds__(256, 2) void attn_kernel(const u16* __restrict__ Qh,
                                                      const u16* __restrict__ Kh,
                                                      const u16* __restrict__ Vt,
                                                      const int* __restrict__ mask,
                                                      u16* __restrict__ attn_out) {
  __shared__ __align__(16) u16 Ks[3][64 * 64];
  __shared__ __align__(16) u16 Vs[3][64 * 64];
  __shared__ __align__(16) float bias2[SS];
  const int tid = threadIdx.x;
  const int l = tid & 63, w = tid >> 6;  // w in 0..3
  // bijective XCD-chunk swizzle: 512 blocks, 8 XCDs, 64 per chunk
  int wg = ((int)blockIdx.x & 7) * 64 + ((int)blockIdx.x >> 3);
  const int qt = wg & 7, h = (wg >> 3) & 15, b = wg >> 7;
  const int lq = l & 15, hi = l >> 4;

  const int* mrow = mask + b * SS;
  for (int i = tid; i < SS; i += 256) bias2[i] = mrow[i] ? 0.0f : -1e13f;

  const size_t bh = (size_t)(b * NHEADS + h);
  const u16* Qp = Qh + bh * ((size_t)SS * DK);
  const u16* Kp = Kh + bh * ((size_t)SS * DK);
  const u16* Vp = Vt + bh * ((size_t)DK * SS);

  const int srow = tid >> 3;
  const int gchunk = (tid & 7) ^ (srow & 7);
  const u16* kg = Kp + (size_t)srow * 64 + gchunk * 8;          // + kv0*64
  const u16* vg = Vp + (size_t)srow * 2048 + gchunk * 8;        // + kv0
  const int ldsbase = w * 512;  // 8 rows * 64 elements per wave (inst0)

#define STAGE(buf, kv0)                                                         \
  do {                                                                          \
    __builtin_amdgcn_global_load_lds(                                           \
        (const __attribute__((address_space(1))) void*)(kg + (size_t)(kv0)*64), \
        (__attribute__((address_space(3))) void*)&Ks[buf][ldsbase], 16, 0, 0);  \
    __builtin_amdgcn_global_load_lds(                                           \
        (const __attribute__((address_space(1))) void*)(kg + (size_t)(kv0)*64 + \
                                                        32 * 64),               \
        (__attribute__((address_space(3))) void*)&Ks[buf][2048 + ldsbase], 16,  \
        0, 0);                                                                  \
    __builtin_amdgcn_global_load_lds(                                           \
        (const __attribute__((address_space(1))) void*)(vg + (kv0)),            \
        (__attribute__((address_space(3))) void*)&Vs[buf][ldsbase], 16, 0, 0);  \
    __builtin_amdgcn_global_load_lds(                                           \
        (const __attribute__((address_space(1))) void*)(vg + (kv0) + 32 * 2048),\
        (__attribute__((address_space(3))) void*)&Vs[buf][2048 + ldsbase], 16,  \
        0, 0);                                                                  \
  } while (0)

  const int q0 = qt * 256 + w * 64;
  short8 qf[4][2];
#pragma unroll
  for (int qg = 0; qg < 4; ++qg)
#pragma unroll
    for (int kd = 0; kd < 2; ++kd)
      qf[qg][kd] = *(const short8*)&Qp[(q0 + qg * 16 + lq) * 64 + kd * 32 + hi * 8];

  f32x4 oacc[4][4] = {};
  f32x4 psv[4] = {};
  const int rx = lq & 7;
  const int csw = ((hi ^ rx) * 8);  // swizzled chunk -> element offset

  auto computeAttn = [&](int it) {
    const int kv0 = it * 64;
    const int kbuf = it % 3;
    // QK all 4 groups: K frags read once, reused 4x
    f32x4 st[4][4];
    __builtin_amdgcn_s_setprio(1);
#pragma unroll
    for (int t = 0; t < 4; ++t) {
      const u16* kp = &Ks[kbuf][(t * 16 + lq) * 64 + csw];
      short8 kf0 = *(const short8*)kp;
      short8 kf1 = *(const short8*)((uintptr_t)kp ^ 64);  // chunk ^4
      f32x4 bz = *(const f32x4*)&bias2[kv0 + t * 16 + hi * 4];
#pragma unroll
      for (int qg = 0; qg < 4; ++qg) {
        f32x4 zz = mfma16(kf0, qf[qg][0], bz);
        st[qg][t] = mfma16(kf1, qf[qg][1], zz);
      }
    }
    __builtin_amdgcn_s_setprio(0);

    // softmax + pack per group (exp2 fused into cvtpk inputs)
    short8 pfA[4], pfB[4];
#pragma unroll
    for (int qg = 0; qg < 4; ++qg) {
      u32 wd[4];
#pragma unroll
      for (int t2 = 0; t2 < 2; ++t2)
#pragma unroll
        for (int p = 0; p < 2; ++p) {
          float plo = __builtin_amdgcn_exp2f(st[qg][t2][2 * p]);
          float phi = __builtin_amdgcn_exp2f(st[qg][t2][2 * p + 1]);
          psv[qg][2 * p] += plo;
          psv[qg][2 * p + 1] += phi;
          wd[t2 * 2 + p] = cvtpk(plo, phi);
        }
      u32 xd[4];
#pragma unroll
      for (int t2 = 0; t2 < 2; ++t2)
#pragma unroll
        for (int p = 0; p < 2; ++p) {
          float plo = __builtin_amdgcn_exp2f(st[qg][2 + t2][2 * p]);
          float phi = __builtin_amdgcn_exp2f(st[qg][2 + t2][2 * p + 1]);
          psv[qg][2 * p] += plo;
          psv[qg][2 * p + 1] += phi;
          xd[t2 * 2 + p] = cvtpk(plo, phi);
        }
      pl32swap(wd[0], wd[2]);
      pl32swap(wd[1], wd[3]);
      pl16swap(wd[0], wd[2]);
      pl16swap(wd[1], wd[3]);
      uint4 pk = {wd[0], wd[1], wd[2], wd[3]};
      pfA[qg] = __builtin_bit_cast(short8, pk);
      pl32swap(xd[0], xd[2]);
      pl32swap(xd[1], xd[3]);
      pl16swap(xd[0], xd[2]);
      pl16swap(xd[1], xd[3]);
      uint4 pk2 = {xd[0], xd[1], xd[2], xd[3]};
      pfB[qg] = __builtin_bit_cast(short8, pk2);
    }

    // PV all 4 groups: V frags read once, reused 4x
    __builtin_amdgcn_s_setprio(1);
#pragma unroll
    for (int dt = 0; dt < 4; ++dt) {
      const u16* vp = &Vs[kbuf][(dt * 16 + lq) * 64 + csw];
      short8 vf0 = *(const short8*)vp;
      short8 vf1 = *(const short8*)((uintptr_t)vp ^ 64);
#pragma unroll
      for (int qg = 0; qg < 4; ++qg) {
        oacc[qg][dt] = mfma16(vf0, pfA[qg], oacc[qg][dt]);
        oacc[qg][dt] = mfma16(vf1, pfB[qg], oacc[qg][dt]);
      }
    }
    __builtin_amdgcn_s_setprio(0);
  };

  STAGE(0, 0);
  STAGE(1, 64);
  __syncthreads();  // one-time full drain: bias2 ds_writes + S0/S1

  for (int it = 0; it < 31; ++it) {
    WAITV4;                             // S(it) landed (S(it+1) may fly)
    __builtin_amdgcn_s_barrier();       // all waves done reading buf[(it-1)%3]
    if (it < 30) STAGE((it + 2) % 3, (it + 2) * 64);
    computeAttn(it);
  }
  WAITV0;
  __builtin_amdgcn_s_barrier();
  computeAttn(31);

#pragma unroll
  for (int qg = 0; qg < 4; ++qg) {
    float lsum = psv[qg][0] + psv[qg][1] + psv[qg][2] + psv[qg][3];
    lsum += __shfl_xor(lsum, 16);
    lsum += __shfl_xor(lsum, 32);
    const float inv = 1.0f / lsum;
    const int q = q0 + qg * 16 + lq;
    const size_t obase = (((size_t)(b * SS + q)) << 10) + h * 64;
#pragma unroll
    for (int dt = 0; dt < 4; ++dt) {
      const int dbase = dt * 16 + hi * 4;
      uint2 pk;
      pk.x = (u32)f2bf(oacc[qg][dt][0] * inv) | ((u32)f2bf(oacc[qg][dt][1] * inv) << 16);
      pk.y = (u32)f2bf(oacc[qg][dt][2] * inv) | ((u32)f2bf(oacc[qg][dt][3] * inv) << 16);
      *(uint2*)&attn_out[obase + dbase] = pk;
    }
  }
#undef STAGE
}

extern "C" void kernel_launch(void* const* d_in, const int* in_sizes, int n_in,
                              void* d_out, int out_size, void* d_ws, size_t ws_size,
                              hipStream_t stream) {
  const float* q_in = (const float*)d_in[0];
  const float* k_in = (const float*)d_in[1];
  const float* v_in = (const float*)d_in[2];
  const int* mask = (const int*)d_in[3];
  const float* Wq = (const float*)d_in[4];
  const float* Wk = (const float*)d_in[5];
  const float* Wv = (const float*)d_in[6];
  const float* Wo = (const float*)d_in[7];

  char* ws = (char*)d_ws;
  const size_t MB = 1ull << 20;
  u16* qb  = (u16*)(ws + 0 * MB);
  u16* kb  = (u16*)(ws + 16 * MB);
  u16* vb  = (u16*)(ws + 32 * MB);
  u16* wqb = (u16*)(ws + 48 * MB);
  u16* wkb = (u16*)(ws + 50 * MB);
  u16* wvb = (u16*)(ws + 52 * MB);
  u16* wob = (u16*)(ws + 54 * MB);
  u16* Qh  = (u16*)(ws + 56 * MB);
  u16* Kh  = (u16*)(ws + 72 * MB);
  u16* Vt  = (u16*)(ws + 88 * MB);
  u16* attn = (u16*)(ws + 104 * MB);  // total 120MB

  const int NX4 = (M_TOT * D_MODEL) / 4;
  const int NW4 = (D_MODEL * D_MODEL) / 4;
  cvt7_kernel<<<dim3(2048, 7), 256, 0, stream>>>(
      q_in, k_in, v_in, Wq, Wk, Wv, Wo,
      qb, kb, vb, wqb, wkb, wvb, wob, NX4, NW4);

  gemm_qkv<<<dim3(512, 1, 3), 256, 0, stream>>>(
      qb, kb, vb, wqb, wkb, wvb, Qh, Kh, Vt);

  attn_kernel<<<512, 256, 0, stream>>>(Qh, Kh, Vt, mask, attn);

  gemm_out<<<512, 256, 0, stream>>>(attn, wob, (float*)d_out);
}